// Round 1
// baseline (142.448 us; speedup 1.0000x reference)
//
#include <hip/hip_runtime.h>
#include <hip/hip_bf16.h>
#include <math.h>

#define EPSF 1e-8f
// dims: B=32, C=384, H=W=32, L=1024, RF=24, RA=48

__device__ __forceinline__ float gelu_exact(float z) {
    return 0.5f * z * (1.0f + erff(z * 0.70710678118654752440f));
}
__device__ __forceinline__ float sigmoidf(float z) {
    return 1.0f / (1.0f + expf(-z));
}
__device__ __forceinline__ float xfreq(float xv, float wcs, float alpha) {
    float rec = wcs * (xv + EPSF);
    rec = fminf(fmaxf(rec, -5.0f), 5.0f);
    return fmaf(alpha, rec, xv);
}

// ---------------- K1: per-image rfft2 magnitudes -> energy[b, 2C] ----------------
// One wave per (b,c) image. Separable DFT: rows (32->17 complex) then cols.
// Rotation recurrence for twiddles (no table lookups). Only the 344 needed bins
// (low: u<8,v<4 ; high: u>=8,v>=4) in stage 2.
__global__ void __launch_bounds__(64) k1_energy(const float* __restrict__ x,
                                                float* __restrict__ energy) {
    __shared__ float img[32][33];   // +1 pad -> conflict-free row reads
    __shared__ float Rre[32][17];
    __shared__ float Rim[32][17];
    const int t = threadIdx.x;
    const int bc = blockIdx.x;
    const float* src = x + (size_t)bc * 1024;
#pragma unroll
    for (int i = 0; i < 16; ++i) {
        int idx = t + 64 * i;
        img[idx >> 5][idx & 31] = src[idx] + EPSF;
    }
    __syncthreads();

    const float step = 6.28318530717958647692f / 32.0f;  // 2*pi/32
    const int h = t >> 1, vh = t & 1;
    float row[32];
#pragma unroll
    for (int w = 0; w < 32; ++w) row[w] = img[h][w];

#pragma unroll 1
    for (int j = 0; j < 9; ++j) {
        int v = vh + 2 * j;
        if (v < 17) {
            float sv, cv;
            sincosf(step * (float)v, &sv, &cv);
            float cr = 1.0f, sr = 0.0f, re = 0.0f, im = 0.0f;
#pragma unroll
            for (int w = 0; w < 32; ++w) {
                re = fmaf(row[w], cr, re);
                im = fmaf(row[w], -sr, im);
                float c2 = fmaf(cr, cv, -sr * sv);
                sr = fmaf(sr, cv, cr * sv);
                cr = c2;
            }
            Rre[h][v] = re;
            Rim[h][v] = im;
        }
    }
    __syncthreads();

    float lowacc = 0.0f, highacc = 0.0f;
#pragma unroll 1
    for (int o = t; o < 344; o += 64) {
        int u, v;
        if (o < 32) { u = o >> 2; v = o & 3; }
        else { int o2 = o - 32; int q = o2 / 13; u = 8 + q; v = 4 + (o2 - 13 * q); }
        float su, cu;
        sincosf(step * (float)u, &su, &cu);
        float cr = 1.0f, sr = 0.0f, re = 0.0f, im = 0.0f;
#pragma unroll
        for (int hh = 0; hh < 32; ++hh) {
            float a = Rre[hh][v], b = Rim[hh][v];
            re = fmaf(a, cr, re); re = fmaf(b, sr, re);
            im = fmaf(b, cr, im); im = fmaf(-a, sr, im);
            float c2 = fmaf(cr, cu, -sr * su);
            sr = fmaf(sr, cu, cr * su);
            cr = c2;
        }
        float mag = sqrtf(fmaf(re, re, im * im)) * (1.0f / 32.0f);  // ortho norm
        if (o < 32) lowacc += mag; else highacc += mag;
    }
#pragma unroll
    for (int off = 32; off > 0; off >>= 1) {
        lowacc  += __shfl_down(lowacc, off, 64);
        highacc += __shfl_down(highacc, off, 64);
    }
    if (t == 0) {
        int b = bc / 384, c = bc - 384 * b;
        energy[b * 768 + c]       = lowacc * (1.0f / 32.0f) + EPSF;   // mean(|xf|)+EPS
        energy[b * 768 + 384 + c] = highacc * (1.0f / 312.0f) + EPSF;
    }
}

// ---------------- K2: wts = sigmoid(gelu(energy@w1+b1)@w2+b2), per b ----------------
__global__ void __launch_bounds__(64) k2_mlp(const float* __restrict__ energy,
                                             const float* __restrict__ w1,
                                             const float* __restrict__ b1,
                                             const float* __restrict__ w2,
                                             const float* __restrict__ b2,
                                             float* __restrict__ wts) {
    __shared__ float e[768];
    __shared__ float hid[24];
    const int b = blockIdx.x, t = threadIdx.x;
    for (int i = t; i < 768; i += 64) e[i] = energy[b * 768 + i];
    __syncthreads();
    if (t < 24) {
        float a = b1[t];
        for (int k = 0; k < 768; ++k) a = fmaf(e[k], w1[k * 24 + t], a);
        hid[t] = gelu_exact(a);
    }
    __syncthreads();
    for (int c = t; c < 384; c += 64) {
        float z = b2[c];
#pragma unroll
        for (int j = 0; j < 24; ++j) z = fmaf(hid[j], w2[j * 384 + c], z);
        wts[b * 384 + c] = sigmoidf(z);
    }
}

// ---------------- K3: LayerNorm stats mu[b,l], r[b,l] over C ----------------
// grid = 32*16 blocks, 256 thr. Wave w covers c in [96w, 96w+96), lane -> l.
__global__ void __launch_bounds__(256) k3_stats(const float* __restrict__ x,
                                                const float* __restrict__ wts,
                                                const float* __restrict__ alp,
                                                float* __restrict__ mu,
                                                float* __restrict__ rr) {
    const int b = blockIdx.x >> 4, lt = blockIdx.x & 15;
    const int t = threadIdx.x, w = t >> 6, lane = t & 63;
    const int l = lt * 64 + lane;
    const float alpha = alp[0];
    const float* xb = x + (size_t)b * 384 * 1024 + l;
    const float* wb = wts + b * 384;
    float s = 0.0f, q = 0.0f;
#pragma unroll 4
    for (int c = w * 96; c < w * 96 + 96; ++c) {
        float xf = xfreq(xb[(size_t)c * 1024], wb[c], alpha);
        s += xf;
        q = fmaf(xf, xf, q);
    }
    __shared__ float ls[4][64], lq[4][64];
    ls[w][lane] = s; lq[w][lane] = q;
    __syncthreads();
    if (t < 64) {
        float S = ls[0][t] + ls[1][t] + ls[2][t] + ls[3][t];
        float Q = lq[0][t] + lq[1][t] + lq[2][t] + lq[3][t];
        float m = S * (1.0f / 384.0f);
        float var = Q * (1.0f / 384.0f) - m * m;
        mu[b * 1024 + lt * 64 + t] = m;
        rr[b * 1024 + lt * 64 + t] = rsqrtf(var + 1e-5f);
    }
}

// ---------------- K4: S[b,c] = sum_l x_f * r ----------------
__global__ void __launch_bounds__(64) k4_S(const float* __restrict__ x,
                                           const float* __restrict__ wts,
                                           const float* __restrict__ alp,
                                           const float* __restrict__ rr,
                                           float* __restrict__ Sarr) {
    const int bc = blockIdx.x, lane = threadIdx.x;
    const int b = bc / 384;
    const float alpha = alp[0];
    const float wcs = wts[bc];
    const float* xr = x + (size_t)bc * 1024;
    const float* rb = rr + b * 1024;
    float acc = 0.0f;
#pragma unroll
    for (int k = 0; k < 16; ++k) {
        int l = lane + 64 * k;
        acc = fmaf(xfreq(xr[l], wcs, alpha), rb[l], acc);
    }
#pragma unroll
    for (int off = 32; off > 0; off >>= 1) acc += __shfl_down(acc, off, 64);
    if (lane == 0) Sarr[bc] = acc;
}

// ---------------- K5: attn4[b,c] = 4*sigmoid(gelu(xg@wg+bg)@wc+bc), per b ----------------
__global__ void __launch_bounds__(384) k5_attn(const float* __restrict__ Sarr,
                                               const float* __restrict__ mu,
                                               const float* __restrict__ rr,
                                               const float* __restrict__ g,
                                               const float* __restrict__ beta,
                                               const float* __restrict__ wg,
                                               const float* __restrict__ bg,
                                               const float* __restrict__ wc,
                                               const float* __restrict__ bc_,
                                               float* __restrict__ attn4) {
    __shared__ float red[6];
    __shared__ float xg[384];
    __shared__ float hid[48];
    const int b = blockIdx.x, t = threadIdx.x;
    const int wv = t >> 6, lane = t & 63;
    // T_b = sum_l mu*r
    float p = 0.0f;
    for (int l = t; l < 1024; l += 384) p += mu[b * 1024 + l] * rr[b * 1024 + l];
#pragma unroll
    for (int off = 32; off > 0; off >>= 1) p += __shfl_down(p, off, 64);
    if (lane == 0) red[wv] = p;
    __syncthreads();
    float T = red[0] + red[1] + red[2] + red[3] + red[4] + red[5];
    xg[t] = fmaf(g[t], (Sarr[b * 384 + t] - T) * (1.0f / 1024.0f), 0.0f) + beta[t];
    __syncthreads();
    if (t < 48) {
        float a = bg[t];
        for (int k = 0; k < 384; ++k) a = fmaf(xg[k], wg[k * 48 + t], a);
        hid[t] = gelu_exact(a);
    }
    __syncthreads();
    float z = bc_[t];
#pragma unroll
    for (int j = 0; j < 48; ++j) z = fmaf(hid[j], wc[j * 384 + t], z);
    attn4[b * 384 + t] = 4.0f * sigmoidf(z);
}

// ---------------- K6: out[b,l,c] = 4 * x_f[b,c,l] * attn[b,c] (LDS transpose) --------
__global__ void __launch_bounds__(256) k6_out(const float* __restrict__ x,
                                              const float* __restrict__ wts,
                                              const float* __restrict__ alp,
                                              const float* __restrict__ attn4,
                                              float* __restrict__ out) {
    __shared__ float tile[64][65];
    const int id = blockIdx.x;
    const int b = id / 96, rem = id - 96 * b;
    const int lt = rem / 6, ct = rem - 6 * lt;
    const int t = threadIdx.x, w = t >> 6, lane = t & 63;
    const float alpha = alp[0];
    const float* xb = x + ((size_t)b * 384 + ct * 64) * 1024 + lt * 64;
#pragma unroll
    for (int i = 0; i < 16; ++i) {
        int cc = w + 4 * i;
        float wcs = wts[b * 384 + ct * 64 + cc];
        float a4  = attn4[b * 384 + ct * 64 + cc];
        float xf = xfreq(xb[(size_t)cc * 1024 + lane], wcs, alpha);
        tile[cc][lane] = xf * a4;
    }
    __syncthreads();
    float* ob = out + ((size_t)b * 1024 + lt * 64) * 384 + ct * 64;
#pragma unroll
    for (int j = 0; j < 16; ++j) {
        int ll = j * 4 + w;
        ob[(size_t)ll * 384 + lane] = tile[lane][ll];
    }
}

extern "C" void kernel_launch(void* const* d_in, const int* in_sizes, int n_in,
                              void* d_out, int out_size, void* d_ws, size_t ws_size,
                              hipStream_t stream) {
    const float* x   = (const float*)d_in[0];
    const float* w1  = (const float*)d_in[1];
    const float* b1  = (const float*)d_in[2];
    const float* w2  = (const float*)d_in[3];
    const float* b2  = (const float*)d_in[4];
    const float* alp = (const float*)d_in[5];
    const float* lng = (const float*)d_in[6];
    const float* lnb = (const float*)d_in[7];
    const float* wg  = (const float*)d_in[8];
    const float* bg  = (const float*)d_in[9];
    const float* wc  = (const float*)d_in[10];
    const float* bc  = (const float*)d_in[11];
    float* out = (float*)d_out;

    float* ws     = (float*)d_ws;
    float* energy = ws;             // 32*768   = 24576
    float* wts    = ws + 24576;     // 32*384   = 12288
    float* mu     = ws + 36864;     // 32*1024  = 32768
    float* rr     = ws + 69632;     // 32*1024  = 32768
    float* Sarr   = ws + 102400;    // 32*384   = 12288
    float* attn4  = ws + 114688;    // 32*384   = 12288  -> total 127 KFloats ~ 508 KB

    k1_energy<<<12288, 64, 0, stream>>>(x, energy);
    k2_mlp<<<32, 64, 0, stream>>>(energy, w1, b1, w2, b2, wts);
    k3_stats<<<512, 256, 0, stream>>>(x, wts, alp, mu, rr);
    k4_S<<<12288, 64, 0, stream>>>(x, wts, alp, rr, Sarr);
    k5_attn<<<32, 384, 0, stream>>>(Sarr, mu, rr, lng, lnb, wg, bg, wc, bc, attn4);
    k6_out<<<3072, 256, 0, stream>>>(x, wts, alp, attn4, out);
}

// Round 2
// 109.759 us; speedup vs baseline: 1.2978x; 1.2978x over previous
//
#include <hip/hip_runtime.h>
#include <hip/hip_bf16.h>
#include <math.h>

#define EPSF 1e-8f
// dims: B=32, C=384, H=W=32, L=1024, RF=24, RA=48

__device__ __forceinline__ float gelu_exact(float z) {
    return 0.5f * z * (1.0f + erff(z * 0.70710678118654752440f));
}
__device__ __forceinline__ float sigmoidf(float z) {
    return 1.0f / (1.0f + expf(-z));
}
__device__ __forceinline__ float xfreq(float xv, float wcs, float alpha) {
    float rec = wcs * (xv + EPSF);
    rec = fminf(fmaxf(rec, -5.0f), 5.0f);
    return fmaf(alpha, rec, xv);
}

// ---------- compile-time twiddles: cos/sin(2*pi*k/32) ----------
constexpr float cqv(int i) {
    return i == 0 ? 1.0f : i == 1 ? 0.980785280403230449f : i == 2 ? 0.923879532511286756f
         : i == 3 ? 0.831469612302545237f : i == 4 ? 0.707106781186547524f
         : i == 5 ? 0.555570233019602225f : i == 6 ? 0.382683432365089772f
         : i == 7 ? 0.195090322016128268f : 0.0f;  // i==8 -> 0
}
constexpr float c32f(int k) {
    k = ((k % 32) + 32) % 32;
    int kk = (k > 16) ? 32 - k : k;
    return (kk <= 8) ? cqv(kk) : -cqv(16 - kk);
}
constexpr float s32f(int k) { return c32f(k - 8); }

// ---------- stage 1: row DFT (along w), literal twiddles ----------
template<int V, int W>
struct S1T {
    static __device__ __forceinline__ void run(const float (&r0)[32], const float (&r1)[32],
                                               float& re0, float& im0, float& re1, float& im1) {
        constexpr float c = c32f(V * W);
        constexpr float s = s32f(V * W);
        if constexpr (c != 0.0f) { re0 = fmaf(r0[W], c, re0); re1 = fmaf(r1[W], c, re1); }
        if constexpr (s != 0.0f) { im0 = fmaf(r0[W], -s, im0); im1 = fmaf(r1[W], -s, im1); }
        if constexpr (W + 1 < 32) S1T<V, W + 1>::run(r0, r1, re0, im0, re1, im1);
    }
};
template<int V>
struct S1V {
    static __device__ __forceinline__ void run(const float (&r0)[32], const float (&r1)[32],
                                               float* Rre, float* Rim, int img, int hp) {
        float re0 = 0.f, im0 = 0.f, re1 = 0.f, im1 = 0.f;
        S1T<V, 0>::run(r0, r1, re0, im0, re1, im1);
        const int base = img * 612 + V * 36 + hp;   // row stride 36 (16B-aligned rows)
        Rre[base] = re0; Rre[base + 16] = re1;
        Rim[base] = im0; Rim[base + 16] = im1;
        if constexpr (V + 1 < 17) S1V<V + 1>::run(r0, r1, Rre, Rim, img, hp);
    }
};

// ---------- stage 2: column DFT (along h), literal twiddles ----------
template<int U, int H>
struct S2T {
    static __device__ __forceinline__ void run(const float (&ar)[32], const float (&ai)[32],
                                               float& re, float& im) {
        constexpr float c = c32f(U * H);
        constexpr float s = s32f(U * H);
        if constexpr (c != 0.0f) { re = fmaf(ar[H], c, re); im = fmaf(ai[H], c, im); }
        if constexpr (s != 0.0f) { re = fmaf(ai[H], s, re); im = fmaf(ar[H], -s, im); }
        if constexpr (H + 1 < 32) S2T<U, H + 1>::run(ar, ai, re, im);
    }
};
template<int U, int UEND>
struct S2U {
    static __device__ __forceinline__ void run(const float (&ar)[32], const float (&ai)[32], float& acc) {
        float re = 0.f, im = 0.f;
        S2T<U, 0>::run(ar, ai, re, im);
        acc += sqrtf(fmaf(re, re, im * im));
        if constexpr (U + 1 < UEND) S2U<U + 1, UEND>::run(ar, ai, acc);
    }
};

// ---------------- K1: per-image rfft2 magnitudes -> energy[b, 2C] ----------------
// One wave = 4 images. Stage1: lane=(img, hp) computes rows hp,hp+16 for v=0..16.
// Stage2 phase-H: lane=(img, j) -> v=4+j, u=8..31 (high). phase-L: lanes<16 -> v<4, u<8 (low).
__global__ void __launch_bounds__(64) k1_energy(const float* __restrict__ x,
                                                float* __restrict__ energy) {
    __shared__ __align__(16) float Rre[4 * 17 * 36];
    __shared__ __align__(16) float Rim[4 * 17 * 36];
    const int t = threadIdx.x;
    const int img = t >> 4;        // 0..3
    const int hp  = t & 15;        // rows hp, hp+16
    const int bc0 = blockIdx.x * 4;
    const float* src = x + (size_t)(bc0 + img) * 1024;

    float r0[32], r1[32];
    {
        const float4* s0 = (const float4*)(src + hp * 32);
        const float4* s1 = (const float4*)(src + (hp + 16) * 32);
#pragma unroll
        for (int k = 0; k < 8; ++k) {
            float4 a = s0[k], b = s1[k];
            r0[4*k+0] = a.x + EPSF; r0[4*k+1] = a.y + EPSF; r0[4*k+2] = a.z + EPSF; r0[4*k+3] = a.w + EPSF;
            r1[4*k+0] = b.x + EPSF; r1[4*k+1] = b.y + EPSF; r1[4*k+2] = b.z + EPSF; r1[4*k+3] = b.w + EPSF;
        }
    }
    S1V<0>::run(r0, r1, Rre, Rim, img, hp);
    __syncthreads();

    // ---- phase H: high bins u in [8,32), v in [4,17) ----
    {
        const int img2 = t >> 4;
        const int j = t & 15;          // v = 4+j, valid j<13
        const int vv = (4 + j > 16) ? 16 : 4 + j;
        const float4* pr = (const float4*)&Rre[img2 * 612 + vv * 36];
        const float4* pi = (const float4*)&Rim[img2 * 612 + vv * 36];
        float ar[32], ai[32];
#pragma unroll
        for (int k = 0; k < 8; ++k) {
            float4 a = pr[k], b = pi[k];
            ar[4*k+0] = a.x; ar[4*k+1] = a.y; ar[4*k+2] = a.z; ar[4*k+3] = a.w;
            ai[4*k+0] = b.x; ai[4*k+1] = b.y; ai[4*k+2] = b.z; ai[4*k+3] = b.w;
        }
        float accH = 0.f;
        S2U<8, 32>::run(ar, ai, accH);
        accH = (j < 13) ? accH : 0.f;   // single NaN-safe mask
        accH += __shfl_xor(accH, 1);
        accH += __shfl_xor(accH, 2);
        accH += __shfl_xor(accH, 4);
        accH += __shfl_xor(accH, 8);
        if (j == 0) {
            const int bc = bc0 + img2;
            const int b = bc / 384, c = bc - b * 384;
            energy[b * 768 + 384 + c] = accH * (1.0f / 9984.0f) + EPSF;  // /(312 bins * 32 norm)
        }
    }
    // ---- phase L: low bins u in [0,8), v in [0,4) ----
    {
        const int img3 = (t >> 2) & 3;  // meaningful for t<16
        const int v3 = t & 3;
        const float4* pr = (const float4*)&Rre[img3 * 612 + v3 * 36];
        const float4* pi = (const float4*)&Rim[img3 * 612 + v3 * 36];
        float ar[32], ai[32];
#pragma unroll
        for (int k = 0; k < 8; ++k) {
            float4 a = pr[k], b = pi[k];
            ar[4*k+0] = a.x; ar[4*k+1] = a.y; ar[4*k+2] = a.z; ar[4*k+3] = a.w;
            ai[4*k+0] = b.x; ai[4*k+1] = b.y; ai[4*k+2] = b.z; ai[4*k+3] = b.w;
        }
        float accL = 0.f;
        S2U<0, 8>::run(ar, ai, accL);
        accL += __shfl_xor(accL, 1);
        accL += __shfl_xor(accL, 2);
        if (t < 16 && v3 == 0) {
            const int bc = bc0 + img3;
            const int b = bc / 384, c = bc - b * 384;
            energy[b * 768 + c] = accL * (1.0f / 1024.0f) + EPSF;  // /(32 bins * 32 norm)
        }
    }
}

// ---------------- K2: wts = sigmoid(gelu(energy@w1+b1)@w2+b2), per b ----------------
__global__ void __launch_bounds__(64) k2_mlp(const float* __restrict__ energy,
                                             const float* __restrict__ w1,
                                             const float* __restrict__ b1,
                                             const float* __restrict__ w2,
                                             const float* __restrict__ b2,
                                             float* __restrict__ wts) {
    __shared__ float e[768];
    __shared__ float hid[24];
    const int b = blockIdx.x, t = threadIdx.x;
    for (int i = t; i < 768; i += 64) e[i] = energy[b * 768 + i];
    __syncthreads();
    if (t < 24) {
        float a = b1[t];
        for (int k = 0; k < 768; ++k) a = fmaf(e[k], w1[k * 24 + t], a);
        hid[t] = gelu_exact(a);
    }
    __syncthreads();
    for (int c = t; c < 384; c += 64) {
        float z = b2[c];
#pragma unroll
        for (int j = 0; j < 24; ++j) z = fmaf(hid[j], w2[j * 384 + c], z);
        wts[b * 384 + c] = sigmoidf(z);
    }
}

// ---------------- K3: LayerNorm stats mu[b,l], r[b,l] over C ----------------
__global__ void __launch_bounds__(256) k3_stats(const float* __restrict__ x,
                                                const float* __restrict__ wts,
                                                const float* __restrict__ alp,
                                                float* __restrict__ mu,
                                                float* __restrict__ rr) {
    const int b = blockIdx.x >> 4, lt = blockIdx.x & 15;
    const int t = threadIdx.x, w = t >> 6, lane = t & 63;
    const int l = lt * 64 + lane;
    const float alpha = alp[0];
    const float* xb = x + (size_t)b * 384 * 1024 + l;
    const float* wb = wts + b * 384;
    float s = 0.0f, q = 0.0f;
#pragma unroll 4
    for (int c = w * 96; c < w * 96 + 96; ++c) {
        float xf = xfreq(xb[(size_t)c * 1024], wb[c], alpha);
        s += xf;
        q = fmaf(xf, xf, q);
    }
    __shared__ float ls[4][64], lq[4][64];
    ls[w][lane] = s; lq[w][lane] = q;
    __syncthreads();
    if (t < 64) {
        float S = ls[0][t] + ls[1][t] + ls[2][t] + ls[3][t];
        float Q = lq[0][t] + lq[1][t] + lq[2][t] + lq[3][t];
        float m = S * (1.0f / 384.0f);
        float var = Q * (1.0f / 384.0f) - m * m;
        mu[b * 1024 + lt * 64 + t] = m;
        rr[b * 1024 + lt * 64 + t] = rsqrtf(var + 1e-5f);
    }
}

// ---------------- K4: S[b,c] = sum_l x_f * r (float4 loads) ----------------
__global__ void __launch_bounds__(64) k4_S(const float* __restrict__ x,
                                           const float* __restrict__ wts,
                                           const float* __restrict__ alp,
                                           const float* __restrict__ rr,
                                           float* __restrict__ Sarr) {
    const int bc = blockIdx.x, lane = threadIdx.x;
    const int b = bc / 384;
    const float alpha = alp[0];
    const float wcs = wts[bc];
    const float4* xr4 = (const float4*)(x + (size_t)bc * 1024);
    const float4* rb4 = (const float4*)(rr + b * 1024);
    float acc = 0.0f;
#pragma unroll
    for (int k = 0; k < 4; ++k) {
        float4 xv = xr4[lane + 64 * k];
        float4 rv = rb4[lane + 64 * k];
        acc = fmaf(xfreq(xv.x, wcs, alpha), rv.x, acc);
        acc = fmaf(xfreq(xv.y, wcs, alpha), rv.y, acc);
        acc = fmaf(xfreq(xv.z, wcs, alpha), rv.z, acc);
        acc = fmaf(xfreq(xv.w, wcs, alpha), rv.w, acc);
    }
#pragma unroll
    for (int off = 32; off > 0; off >>= 1) acc += __shfl_down(acc, off, 64);
    if (lane == 0) Sarr[bc] = acc;
}

// ---------------- K5: attn4[b,c] = 4*sigmoid(gelu(xg@wg+bg)@wc+bc), per b ----------------
__global__ void __launch_bounds__(384) k5_attn(const float* __restrict__ Sarr,
                                               const float* __restrict__ mu,
                                               const float* __restrict__ rr,
                                               const float* __restrict__ g,
                                               const float* __restrict__ beta,
                                               const float* __restrict__ wg,
                                               const float* __restrict__ bg,
                                               const float* __restrict__ wc,
                                               const float* __restrict__ bc_,
                                               float* __restrict__ attn4) {
    __shared__ float red[6];
    __shared__ float xg[384];
    __shared__ float hid[48];
    const int b = blockIdx.x, t = threadIdx.x;
    const int wv = t >> 6, lane = t & 63;
    float p = 0.0f;
    for (int l = t; l < 1024; l += 384) p += mu[b * 1024 + l] * rr[b * 1024 + l];
#pragma unroll
    for (int off = 32; off > 0; off >>= 1) p += __shfl_down(p, off, 64);
    if (lane == 0) red[wv] = p;
    __syncthreads();
    float T = red[0] + red[1] + red[2] + red[3] + red[4] + red[5];
    xg[t] = fmaf(g[t], (Sarr[b * 384 + t] - T) * (1.0f / 1024.0f), 0.0f) + beta[t];
    __syncthreads();
    if (t < 48) {
        float a = bg[t];
        for (int k = 0; k < 384; ++k) a = fmaf(xg[k], wg[k * 48 + t], a);
        hid[t] = gelu_exact(a);
    }
    __syncthreads();
    float z = bc_[t];
#pragma unroll
    for (int j = 0; j < 48; ++j) z = fmaf(hid[j], wc[j * 384 + t], z);
    attn4[b * 384 + t] = 4.0f * sigmoidf(z);
}

// ---------------- K6: out[b,l,c] = 4 * x_f[b,c,l] * attn[b,c] (LDS transpose, float4 stores) ---
__global__ void __launch_bounds__(256) k6_out(const float* __restrict__ x,
                                              const float* __restrict__ wts,
                                              const float* __restrict__ alp,
                                              const float* __restrict__ attn4,
                                              float* __restrict__ out) {
    __shared__ float tile[64][65];
    const int id = blockIdx.x;
    const int b = id / 96, rem = id - 96 * b;
    const int lt = rem / 6, ct = rem - 6 * lt;
    const int t = threadIdx.x, w = t >> 6, lane = t & 63;
    const float alpha = alp[0];
    const float* xb = x + ((size_t)b * 384 + ct * 64) * 1024 + lt * 64;
#pragma unroll
    for (int i = 0; i < 16; ++i) {
        int cc = w + 4 * i;
        float wcs = wts[b * 384 + ct * 64 + cc];
        float a4  = attn4[b * 384 + ct * 64 + cc];
        float xf = xfreq(xb[(size_t)cc * 1024 + lane], wcs, alpha);
        tile[cc][lane] = xf * a4;
    }
    __syncthreads();
    const int c4 = (t & 15) * 4;   // 16 float4 chunks across 64 c's
    const int lb = t >> 4;         // 0..15 base rows
    float* ob = out + ((size_t)b * 1024 + lt * 64) * 384 + ct * 64;
#pragma unroll
    for (int rep = 0; rep < 4; ++rep) {
        int ll = rep * 16 + lb;
        float4 v;
        v.x = tile[c4 + 0][ll];
        v.y = tile[c4 + 1][ll];
        v.z = tile[c4 + 2][ll];
        v.w = tile[c4 + 3][ll];
        *(float4*)(ob + (size_t)ll * 384 + c4) = v;
    }
}

extern "C" void kernel_launch(void* const* d_in, const int* in_sizes, int n_in,
                              void* d_out, int out_size, void* d_ws, size_t ws_size,
                              hipStream_t stream) {
    const float* x   = (const float*)d_in[0];
    const float* w1  = (const float*)d_in[1];
    const float* b1  = (const float*)d_in[2];
    const float* w2  = (const float*)d_in[3];
    const float* b2  = (const float*)d_in[4];
    const float* alp = (const float*)d_in[5];
    const float* lng = (const float*)d_in[6];
    const float* lnb = (const float*)d_in[7];
    const float* wg  = (const float*)d_in[8];
    const float* bg  = (const float*)d_in[9];
    const float* wc  = (const float*)d_in[10];
    const float* bc  = (const float*)d_in[11];
    float* out = (float*)d_out;

    float* ws     = (float*)d_ws;
    float* energy = ws;             // 32*768   = 24576
    float* wts    = ws + 24576;     // 32*384   = 12288
    float* mu     = ws + 36864;     // 32*1024  = 32768
    float* rr     = ws + 69632;     // 32*1024  = 32768
    float* Sarr   = ws + 102400;    // 32*384   = 12288
    float* attn4  = ws + 114688;    // 32*384   = 12288

    k1_energy<<<3072, 64, 0, stream>>>(x, energy);
    k2_mlp<<<32, 64, 0, stream>>>(energy, w1, b1, w2, b2, wts);
    k3_stats<<<512, 256, 0, stream>>>(x, wts, alp, mu, rr);
    k4_S<<<12288, 64, 0, stream>>>(x, wts, alp, rr, Sarr);
    k5_attn<<<32, 384, 0, stream>>>(Sarr, mu, rr, lng, lnb, wg, bg, wc, bc, attn4);
    k6_out<<<3072, 256, 0, stream>>>(x, wts, alp, attn4, out);
}

// Round 3
// 104.767 us; speedup vs baseline: 1.3597x; 1.0477x over previous
//
#include <hip/hip_runtime.h>
#include <hip/hip_bf16.h>
#include <math.h>

#define EPSF 1e-8f
// dims: B=32, C=384, H=W=32, L=1024, RF=24, RA=48

__device__ __forceinline__ float gelu_exact(float z) {
    return 0.5f * z * (1.0f + erff(z * 0.70710678118654752440f));
}
__device__ __forceinline__ float sigmoidf(float z) {
    return 1.0f / (1.0f + expf(-z));
}
__device__ __forceinline__ float xfreq(float xv, float wcs, float alpha) {
    float rec = wcs * (xv + EPSF);
    rec = fminf(fmaxf(rec, -5.0f), 5.0f);
    return fmaf(alpha, rec, xv);
}

// bf16 pack/unpack (T12 recipe: no builtin for cvt_pk on gfx950, inline asm)
__device__ __forceinline__ unsigned pk_bf16(float lo, float hi) {
    unsigned r;
    asm("v_cvt_pk_bf16_f32 %0, %1, %2" : "=v"(r) : "v"(lo), "v"(hi));
    return r;
}
__device__ __forceinline__ float ubf_lo(unsigned u) { return __uint_as_float(u << 16); }
__device__ __forceinline__ float ubf_hi(unsigned u) { return __uint_as_float(u & 0xFFFF0000u); }

// ---------- compile-time twiddles: cos/sin(2*pi*k/32) ----------
constexpr float cqv(int i) {
    return i == 0 ? 1.0f : i == 1 ? 0.980785280403230449f : i == 2 ? 0.923879532511286756f
         : i == 3 ? 0.831469612302545237f : i == 4 ? 0.707106781186547524f
         : i == 5 ? 0.555570233019602225f : i == 6 ? 0.382683432365089772f
         : i == 7 ? 0.195090322016128268f : 0.0f;  // i==8 -> 0
}
constexpr float c32f(int k) {
    k = ((k % 32) + 32) % 32;
    int kk = (k > 16) ? 32 - k : k;
    return (kk <= 8) ? cqv(kk) : -cqv(16 - kk);
}
constexpr float s32f(int k) { return c32f(k - 8); }

// ---------- stage 1: row DFT (along w), literal twiddles ----------
template<int V, int W>
struct S1T {
    static __device__ __forceinline__ void run(const float (&r0)[32], const float (&r1)[32],
                                               float& re0, float& im0, float& re1, float& im1) {
        constexpr float c = c32f(V * W);
        constexpr float s = s32f(V * W);
        if constexpr (c != 0.0f) { re0 = fmaf(r0[W], c, re0); re1 = fmaf(r1[W], c, re1); }
        if constexpr (s != 0.0f) { im0 = fmaf(r0[W], -s, im0); im1 = fmaf(r1[W], -s, im1); }
        if constexpr (W + 1 < 32) S1T<V, W + 1>::run(r0, r1, re0, im0, re1, im1);
    }
};
template<int V>
struct S1V {
    static __device__ __forceinline__ void run(const float (&r0)[32], const float (&r1)[32],
                                               unsigned* Rp, int img, int hp) {
        float re0 = 0.f, im0 = 0.f, re1 = 0.f, im1 = 0.f;
        S1T<V, 0>::run(r0, r1, re0, im0, re1, im1);
        const int base = img * 612 + V * 36 + hp;   // row stride 36 words (16B-aligned rows)
        Rp[base]      = pk_bf16(re0, im0);
        Rp[base + 16] = pk_bf16(re1, im1);
        if constexpr (V + 1 < 17) S1V<V + 1>::run(r0, r1, Rp, img, hp);
    }
};

// ---------- stage 2: column DFT (along h), literal twiddles ----------
template<int U, int H>
struct S2T {
    static __device__ __forceinline__ void run(const float (&ar)[32], const float (&ai)[32],
                                               float& re, float& im) {
        constexpr float c = c32f(U * H);
        constexpr float s = s32f(U * H);
        if constexpr (c != 0.0f) { re = fmaf(ar[H], c, re); im = fmaf(ai[H], c, im); }
        if constexpr (s != 0.0f) { re = fmaf(ai[H], s, re); im = fmaf(ar[H], -s, im); }
        if constexpr (H + 1 < 32) S2T<U, H + 1>::run(ar, ai, re, im);
    }
};
template<int U, int UEND>
struct S2U {
    static __device__ __forceinline__ void run(const float (&ar)[32], const float (&ai)[32], float& acc) {
        float re = 0.f, im = 0.f;
        S2T<U, 0>::run(ar, ai, re, im);
        acc += sqrtf(fmaf(re, re, im * im));
        if constexpr (U + 1 < UEND) S2U<U + 1, UEND>::run(ar, ai, acc);
    }
};

__device__ __forceinline__ void unpack32(const uint4* p, float (&ar)[32], float (&ai)[32]) {
#pragma unroll
    for (int k = 0; k < 8; ++k) {
        uint4 q = p[k];
        ar[4*k+0] = ubf_lo(q.x); ai[4*k+0] = ubf_hi(q.x);
        ar[4*k+1] = ubf_lo(q.y); ai[4*k+1] = ubf_hi(q.y);
        ar[4*k+2] = ubf_lo(q.z); ai[4*k+2] = ubf_hi(q.z);
        ar[4*k+3] = ubf_lo(q.w); ai[4*k+3] = ubf_hi(q.w);
    }
}

// ---------------- K1: per-image rfft2 magnitudes -> energy[b, 2C] ----------------
// One wave = 4 images. LDS holds bf16-packed row spectra: 4*17*36*4B = 9792 B
// -> 16 blocks/CU resident (all 12 blocks/CU of work co-resident).
__global__ void __launch_bounds__(64) k1_energy(const float* __restrict__ x,
                                                float* __restrict__ energy) {
    __shared__ __align__(16) unsigned Rp[4 * 17 * 36];
    const int t = threadIdx.x;
    const int img = t >> 4;        // 0..3
    const int hp  = t & 15;        // rows hp, hp+16
    const int bc0 = blockIdx.x * 4;
    const float* src = x + (size_t)(bc0 + img) * 1024;

    float r0[32], r1[32];
    {
        const float4* s0 = (const float4*)(src + hp * 32);
        const float4* s1 = (const float4*)(src + (hp + 16) * 32);
#pragma unroll
        for (int k = 0; k < 8; ++k) {
            float4 a = s0[k], b = s1[k];
            r0[4*k+0] = a.x + EPSF; r0[4*k+1] = a.y + EPSF; r0[4*k+2] = a.z + EPSF; r0[4*k+3] = a.w + EPSF;
            r1[4*k+0] = b.x + EPSF; r1[4*k+1] = b.y + EPSF; r1[4*k+2] = b.z + EPSF; r1[4*k+3] = b.w + EPSF;
        }
    }
    S1V<0>::run(r0, r1, Rp, img, hp);
    __syncthreads();

    // ---- phase H: high bins u in [8,32), v in [4,17) ----
    {
        const int j = t & 15;          // v = 4+j, valid j<13
        const int vv = (4 + j > 16) ? 16 : 4 + j;
        float ar[32], ai[32];
        unpack32((const uint4*)&Rp[img * 612 + vv * 36], ar, ai);
        float accH = 0.f;
        S2U<8, 32>::run(ar, ai, accH);
        accH = (j < 13) ? accH : 0.f;   // single NaN-safe mask
        accH += __shfl_xor(accH, 1);
        accH += __shfl_xor(accH, 2);
        accH += __shfl_xor(accH, 4);
        accH += __shfl_xor(accH, 8);
        if (j == 0) {
            const int bc = bc0 + img;
            const int b = bc / 384, c = bc - b * 384;
            energy[b * 768 + 384 + c] = accH * (1.0f / 9984.0f) + EPSF;  // /(312 bins * 32 norm)
        }
    }
    // ---- phase L: low bins u in [0,8), v in [0,4) ----
    {
        const int img3 = (t >> 2) & 3;  // meaningful for t<16
        const int v3 = t & 3;
        float ar[32], ai[32];
        unpack32((const uint4*)&Rp[img3 * 612 + v3 * 36], ar, ai);
        float accL = 0.f;
        S2U<0, 8>::run(ar, ai, accL);
        accL += __shfl_xor(accL, 1);
        accL += __shfl_xor(accL, 2);
        if (t < 16 && v3 == 0) {
            const int bc = bc0 + img3;
            const int b = bc / 384, c = bc - b * 384;
            energy[b * 768 + c] = accL * (1.0f / 1024.0f) + EPSF;  // /(32 bins * 32 norm)
        }
    }
}

// ---------------- K2: wts = sigmoid(gelu(energy@w1+b1)@w2+b2), per b ----------------
__global__ void __launch_bounds__(64) k2_mlp(const float* __restrict__ energy,
                                             const float* __restrict__ w1,
                                             const float* __restrict__ b1,
                                             const float* __restrict__ w2,
                                             const float* __restrict__ b2,
                                             float* __restrict__ wts) {
    __shared__ float e[768];
    __shared__ float hid[24];
    const int b = blockIdx.x, t = threadIdx.x;
    for (int i = t; i < 768; i += 64) e[i] = energy[b * 768 + i];
    __syncthreads();
    if (t < 24) {
        float a0 = 0.f, a1 = 0.f, a2 = 0.f, a3 = 0.f;
        for (int k = 0; k < 768; k += 4) {
            a0 = fmaf(e[k+0], w1[(k+0) * 24 + t], a0);
            a1 = fmaf(e[k+1], w1[(k+1) * 24 + t], a1);
            a2 = fmaf(e[k+2], w1[(k+2) * 24 + t], a2);
            a3 = fmaf(e[k+3], w1[(k+3) * 24 + t], a3);
        }
        hid[t] = gelu_exact(((a0 + a1) + (a2 + a3)) + b1[t]);
    }
    __syncthreads();
    for (int c = t; c < 384; c += 64) {
        float z = b2[c];
#pragma unroll
        for (int j = 0; j < 24; ++j) z = fmaf(hid[j], w2[j * 384 + c], z);
        wts[b * 384 + c] = sigmoidf(z);
    }
}

// ---------------- K3: LayerNorm stats mu[b,l], r[b,l] over C ----------------
// grid = 32*32 (l-tiles of 32), block 256: 8 c-chunks of 48 per thread.
__global__ void __launch_bounds__(256) k3_stats(const float* __restrict__ x,
                                                const float* __restrict__ wts,
                                                const float* __restrict__ alp,
                                                float* __restrict__ mu,
                                                float* __restrict__ rr) {
    const int b = blockIdx.x >> 5, lt = blockIdx.x & 31;
    const int t = threadIdx.x, w8 = t >> 5, l5 = t & 31;
    const int l = lt * 32 + l5;
    const float alpha = alp[0];
    const float* xb = x + (size_t)b * 393216 + l;
    const float* wb = wts + b * 384;
    float s = 0.0f, q = 0.0f;
#pragma unroll 6
    for (int c = w8 * 48; c < w8 * 48 + 48; ++c) {
        float xf = xfreq(xb[(size_t)c * 1024], wb[c], alpha);
        s += xf;
        q = fmaf(xf, xf, q);
    }
    __shared__ float ls[8][32], lq[8][32];
    ls[w8][l5] = s; lq[w8][l5] = q;
    __syncthreads();
    if (t < 32) {
        float S = 0.f, Q = 0.f;
#pragma unroll
        for (int i = 0; i < 8; ++i) { S += ls[i][t]; Q += lq[i][t]; }
        float m = S * (1.0f / 384.0f);
        float var = Q * (1.0f / 384.0f) - m * m;
        mu[b * 1024 + lt * 32 + t] = m;
        rr[b * 1024 + lt * 32 + t] = rsqrtf(var + 1e-5f);
    }
}

// ---------------- K4: S[b,c] = sum_l x_f * r (float4 loads) ----------------
__global__ void __launch_bounds__(64) k4_S(const float* __restrict__ x,
                                           const float* __restrict__ wts,
                                           const float* __restrict__ alp,
                                           const float* __restrict__ rr,
                                           float* __restrict__ Sarr) {
    const int bc = blockIdx.x, lane = threadIdx.x;
    const int b = bc / 384;
    const float alpha = alp[0];
    const float wcs = wts[bc];
    const float4* xr4 = (const float4*)(x + (size_t)bc * 1024);
    const float4* rb4 = (const float4*)(rr + b * 1024);
    float acc = 0.0f;
#pragma unroll
    for (int k = 0; k < 4; ++k) {
        float4 xv = xr4[lane + 64 * k];
        float4 rv = rb4[lane + 64 * k];
        acc = fmaf(xfreq(xv.x, wcs, alpha), rv.x, acc);
        acc = fmaf(xfreq(xv.y, wcs, alpha), rv.y, acc);
        acc = fmaf(xfreq(xv.z, wcs, alpha), rv.z, acc);
        acc = fmaf(xfreq(xv.w, wcs, alpha), rv.w, acc);
    }
#pragma unroll
    for (int off = 32; off > 0; off >>= 1) acc += __shfl_down(acc, off, 64);
    if (lane == 0) Sarr[bc] = acc;
}

// ---------------- K5: attn4[b,c] = 4*sigmoid(gelu(xg@wg+bg)@wc+bc), per b ----------------
__global__ void __launch_bounds__(384) k5_attn(const float* __restrict__ Sarr,
                                               const float* __restrict__ mu,
                                               const float* __restrict__ rr,
                                               const float* __restrict__ g,
                                               const float* __restrict__ beta,
                                               const float* __restrict__ wg,
                                               const float* __restrict__ bg,
                                               const float* __restrict__ wc,
                                               const float* __restrict__ bc_,
                                               float* __restrict__ attn4) {
    __shared__ float red[6];
    __shared__ float xg[384];
    __shared__ float hid[48];
    const int b = blockIdx.x, t = threadIdx.x;
    const int wv = t >> 6, lane = t & 63;
    float p = 0.0f;
    for (int l = t; l < 1024; l += 384) p += mu[b * 1024 + l] * rr[b * 1024 + l];
#pragma unroll
    for (int off = 32; off > 0; off >>= 1) p += __shfl_down(p, off, 64);
    if (lane == 0) red[wv] = p;
    __syncthreads();
    float T = red[0] + red[1] + red[2] + red[3] + red[4] + red[5];
    xg[t] = fmaf(g[t], (Sarr[b * 384 + t] - T) * (1.0f / 1024.0f), 0.0f) + beta[t];
    __syncthreads();
    if (t < 48) {
        float a0 = 0.f, a1 = 0.f, a2 = 0.f, a3 = 0.f;
        for (int k = 0; k < 384; k += 4) {
            a0 = fmaf(xg[k+0], wg[(k+0) * 48 + t], a0);
            a1 = fmaf(xg[k+1], wg[(k+1) * 48 + t], a1);
            a2 = fmaf(xg[k+2], wg[(k+2) * 48 + t], a2);
            a3 = fmaf(xg[k+3], wg[(k+3) * 48 + t], a3);
        }
        hid[t] = gelu_exact(((a0 + a1) + (a2 + a3)) + bg[t]);
    }
    __syncthreads();
    float z = bc_[t];
#pragma unroll
    for (int j = 0; j < 48; ++j) z = fmaf(hid[j], wc[j * 384 + t], z);
    attn4[b * 384 + t] = 4.0f * sigmoidf(z);
}

// ---------------- K6: out[b,l,c] = 4 * x_f[b,c,l] * attn[b,c] (LDS transpose, float4 stores) ---
__global__ void __launch_bounds__(256) k6_out(const float* __restrict__ x,
                                              const float* __restrict__ wts,
                                              const float* __restrict__ alp,
                                              const float* __restrict__ attn4,
                                              float* __restrict__ out) {
    __shared__ float tile[64][65];
    const int id = blockIdx.x;
    const int b = id / 96, rem = id - 96 * b;
    const int lt = rem / 6, ct = rem - 6 * lt;
    const int t = threadIdx.x, w = t >> 6, lane = t & 63;
    const float alpha = alp[0];
    const float* xb = x + ((size_t)b * 384 + ct * 64) * 1024 + lt * 64;
#pragma unroll
    for (int i = 0; i < 16; ++i) {
        int cc = w + 4 * i;
        float wcs = wts[b * 384 + ct * 64 + cc];
        float a4  = attn4[b * 384 + ct * 64 + cc];
        float xf = xfreq(xb[(size_t)cc * 1024 + lane], wcs, alpha);
        tile[cc][lane] = xf * a4;
    }
    __syncthreads();
    const int c4 = (t & 15) * 4;
    const int lb = t >> 4;
    float* ob = out + ((size_t)b * 1024 + lt * 64) * 384 + ct * 64;
#pragma unroll
    for (int rep = 0; rep < 4; ++rep) {
        int ll = rep * 16 + lb;
        float4 v;
        v.x = tile[c4 + 0][ll];
        v.y = tile[c4 + 1][ll];
        v.z = tile[c4 + 2][ll];
        v.w = tile[c4 + 3][ll];
        *(float4*)(ob + (size_t)ll * 384 + c4) = v;
    }
}

extern "C" void kernel_launch(void* const* d_in, const int* in_sizes, int n_in,
                              void* d_out, int out_size, void* d_ws, size_t ws_size,
                              hipStream_t stream) {
    const float* x   = (const float*)d_in[0];
    const float* w1  = (const float*)d_in[1];
    const float* b1  = (const float*)d_in[2];
    const float* w2  = (const float*)d_in[3];
    const float* b2  = (const float*)d_in[4];
    const float* alp = (const float*)d_in[5];
    const float* lng = (const float*)d_in[6];
    const float* lnb = (const float*)d_in[7];
    const float* wg  = (const float*)d_in[8];
    const float* bg  = (const float*)d_in[9];
    const float* wc  = (const float*)d_in[10];
    const float* bc  = (const float*)d_in[11];
    float* out = (float*)d_out;

    float* ws     = (float*)d_ws;
    float* energy = ws;             // 32*768   = 24576
    float* wts    = ws + 24576;     // 32*384   = 12288
    float* mu     = ws + 36864;     // 32*1024  = 32768
    float* rr     = ws + 69632;     // 32*1024  = 32768
    float* Sarr   = ws + 102400;    // 32*384   = 12288
    float* attn4  = ws + 114688;    // 32*384   = 12288

    k1_energy<<<3072, 64, 0, stream>>>(x, energy);
    k2_mlp<<<32, 64, 0, stream>>>(energy, w1, b1, w2, b2, wts);
    k3_stats<<<1024, 256, 0, stream>>>(x, wts, alp, mu, rr);
    k4_S<<<12288, 64, 0, stream>>>(x, wts, alp, rr, Sarr);
    k5_attn<<<32, 384, 0, stream>>>(Sarr, mu, rr, lng, lnb, wg, bg, wc, bc, attn4);
    k6_out<<<3072, 256, 0, stream>>>(x, wts, alp, attn4, out);
}

// Round 4
// 104.525 us; speedup vs baseline: 1.3628x; 1.0023x over previous
//
#include <hip/hip_runtime.h>
#include <hip/hip_bf16.h>
#include <math.h>

#define EPSF 1e-8f
// dims: B=32, C=384, H=W=32, L=1024, RF=24, RA=48

__device__ __forceinline__ float gelu_exact(float z) {
    return 0.5f * z * (1.0f + erff(z * 0.70710678118654752440f));
}
__device__ __forceinline__ float sigmoidf(float z) {
    return 1.0f / (1.0f + expf(-z));
}

// bf16 pack/unpack (no cvt_pk builtin on gfx950 -> inline asm)
__device__ __forceinline__ unsigned pk_bf16(float lo, float hi) {
    unsigned r;
    asm("v_cvt_pk_bf16_f32 %0, %1, %2" : "=v"(r) : "v"(lo), "v"(hi));
    return r;
}
__device__ __forceinline__ float ubf_lo(unsigned u) { return __uint_as_float(u << 16); }
__device__ __forceinline__ float ubf_hi(unsigned u) { return __uint_as_float(u & 0xFFFF0000u); }

// ---------- compile-time twiddles: cos/sin(2*pi*k/32) ----------
constexpr float cqv(int i) {
    return i == 0 ? 1.0f : i == 1 ? 0.980785280403230449f : i == 2 ? 0.923879532511286756f
         : i == 3 ? 0.831469612302545237f : i == 4 ? 0.707106781186547524f
         : i == 5 ? 0.555570233019602225f : i == 6 ? 0.382683432365089772f
         : i == 7 ? 0.195090322016128268f : 0.0f;  // i==8 -> 0
}
constexpr float c32f(int k) {
    k = ((k % 32) + 32) % 32;
    int kk = (k > 16) ? 32 - k : k;
    return (kk <= 8) ? cqv(kk) : -cqv(16 - kk);
}
constexpr float s32f(int k) { return c32f(k - 8); }

// ---------- stage 1: row DFT (along w), 1 row per lane ----------
template<int V, int W>
struct S1T {
    static __device__ __forceinline__ void run(const float (&r)[32], float& re, float& im) {
        constexpr float c = c32f(V * W);
        constexpr float s = s32f(V * W);
        if constexpr (c != 0.0f) re = fmaf(r[W], c, re);
        if constexpr (s != 0.0f) im = fmaf(r[W], -s, im);
        if constexpr (W + 1 < 32) S1T<V, W + 1>::run(r, re, im);
    }
};
template<int V>
struct S1V {
    static __device__ __forceinline__ void run(const float (&r)[32], unsigned* Rp, int base) {
        float re = 0.f, im = 0.f;
        S1T<V, 0>::run(r, re, im);
        Rp[base + V * 33] = pk_bf16(re, im);
        if constexpr (V + 1 < 17) S1V<V + 1>::run(r, Rp, base);
    }
};

// ---------- stage 2 kernel: complex dot with literal twiddles, N samples ----------
template<int U, int H, int HEND, int N>
struct S2T {
    static __device__ __forceinline__ void run(const float (&ar)[N], const float (&ai)[N],
                                               float& re, float& im) {
        constexpr float c = c32f(U * H);
        constexpr float s = s32f(U * H);
        if constexpr (c != 0.0f) { re = fmaf(ar[H], c, re); im = fmaf(ai[H], c, im); }
        if constexpr (s != 0.0f) { re = fmaf(ai[H], s, re); im = fmaf(ar[H], -s, im); }
        if constexpr (H + 1 < HEND) S2T<U, H + 1, HEND, N>::run(ar, ai, re, im);
    }
};

// high bins u in [8,32): 16-h half-partial, sign-fix odd u, pair combine, mag
template<int U>
struct HighU {
    static __device__ __forceinline__ void run(const float (&dr)[16], const float (&di)[16],
                                               float sgn, float& acc) {
        float re = 0.f, im = 0.f;
        S2T<U, 0, 16, 16>::run(dr, di, re, im);
        if constexpr (U & 1) { re *= sgn; im *= sgn; }
        float tr = re + __shfl_xor(re, 1);
        float ti = im + __shfl_xor(im, 1);
        acc += sqrtf(fmaf(tr, tr, ti * ti));
        if constexpr (U + 1 < 32) HighU<U + 1>::run(dr, di, sgn, acc);
    }
};

// low bins u in [0,8): 4-sample partial, rotate by w_k(u)=e^{-i pi u k/4}, 8-lane reduce, mag
template<int U>
struct LowU {
    static __device__ __forceinline__ void run(const float (&er)[4], const float (&ei)[4],
                                               float wre, float wim, float brc, float brs,
                                               float& acc) {
        float pr = 0.f, pi = 0.f;
        S2T<U, 0, 4, 4>::run(er, ei, pr, pi);
        float vr = pr * wre - pi * wim;
        float vi = pr * wim + pi * wre;
        vr += __shfl_xor(vr, 1); vi += __shfl_xor(vi, 1);
        vr += __shfl_xor(vr, 2); vi += __shfl_xor(vi, 2);
        vr += __shfl_xor(vr, 4); vi += __shfl_xor(vi, 4);
        acc += sqrtf(fmaf(vr, vr, vi * vi));
        if constexpr (U + 1 < 8) {
            float nre = fmaf(wre, brc, -wim * brs);
            float nim = fmaf(wre, brs, wim * brc);
            LowU<U + 1>::run(er, ei, nre, nim, brc, brs, acc);
        }
    }
};

// ---------------- K1: per-image rfft2 magnitudes -> energy[b, 2C] ----------------
// One wave = 2 images (grid 6144 -> 24 waves/CU). LDS: bf16-packed [img][v][h],
// v-stride 33 words (<=2-way banks), 4488 B/block.
__global__ void __launch_bounds__(64, 6) k1_energy(const float* __restrict__ x,
                                                   float* __restrict__ energy) {
    __shared__ __align__(16) unsigned Rp[2 * 561];
    const int t = threadIdx.x;
    const int img = t >> 5, h = t & 31;
    const int bc0 = blockIdx.x * 2;
    const float4* src = (const float4*)(x + (size_t)(bc0 + img) * 1024 + h * 32);
    float r[32];
#pragma unroll
    for (int k = 0; k < 8; ++k) {
        float4 a = src[k];
        r[4*k+0] = a.x + EPSF; r[4*k+1] = a.y + EPSF;
        r[4*k+2] = a.z + EPSF; r[4*k+3] = a.w + EPSF;
    }
    S1V<0>::run(r, Rp, img * 561 + h);
    __syncthreads();

    const int q = t & 31;
    // ---- high phase: 13 columns (v=4..16) x 2 h-halves = 26 tasks/img ----
    float acch = 0.f;
    {
        const int vq = (q < 26) ? (4 + (q >> 1)) : 4;
        const int h0 = (q < 26) ? ((q & 1) << 4) : 0;
        const unsigned* bp = &Rp[img * 561 + vq * 33 + h0];
        float dr[16], di[16];
#pragma unroll
        for (int k = 0; k < 16; ++k) { unsigned u = bp[k]; dr[k] = ubf_lo(u); di[k] = ubf_hi(u); }
        const float sgn = (h0 != 0) ? -1.0f : 1.0f;
        HighU<8>::run(dr, di, sgn, acch);
    }
    // ---- low phase: 4 columns (v=0..3) x 8 h-eighths = 32 tasks/img (all lanes) ----
    float accl = 0.f;
    {
        const int v2 = q >> 3, k8 = q & 7;
        const unsigned* lp = &Rp[img * 561 + v2 * 33 + k8 * 4];
        float er[4], ei[4];
#pragma unroll
        for (int j = 0; j < 4; ++j) { unsigned u = lp[j]; er[j] = ubf_lo(u); ei[j] = ubf_hi(u); }
        float sb, cb;
        sincosf(0.78539816339744831f * (float)k8, &sb, &cb);
        LowU<0>::run(er, ei, 1.0f, 0.0f, cb, -sb, accl);
    }
    // ---- reduce per img (32 lanes): high pairs double-counted (x2), low 8x ----
    float hv = (q < 26) ? acch : 0.f;
#pragma unroll
    for (int off = 1; off <= 16; off <<= 1) {
        hv   += __shfl_xor(hv, off);
        accl += __shfl_xor(accl, off);
    }
    if (q == 0) {
        const int bc = bc0 + img;
        const int b = bc / 384, c = bc - 384 * b;
        energy[b * 768 + c]       = accl * (1.0f / 8192.0f)  + EPSF;  // /(8 dup * 32 bins * 32 norm)
        energy[b * 768 + 384 + c] = hv   * (1.0f / 19968.0f) + EPSF;  // /(2 dup * 312 bins * 32 norm)
    }
}

// ---------------- K2: gw = 1 + alpha*sigmoid(gelu(energy@w1+b1)@w2+b2), per b ----------------
__global__ void __launch_bounds__(64) k2_mlp(const float* __restrict__ energy,
                                             const float* __restrict__ w1,
                                             const float* __restrict__ b1,
                                             const float* __restrict__ w2,
                                             const float* __restrict__ b2,
                                             const float* __restrict__ alp,
                                             float* __restrict__ gw) {
    __shared__ float e[768];
    __shared__ float hid[24];
    const int b = blockIdx.x, t = threadIdx.x;
    for (int i = t; i < 768; i += 64) e[i] = energy[b * 768 + i];
    __syncthreads();
    if (t < 24) {
        float a0 = 0.f, a1 = 0.f, a2 = 0.f, a3 = 0.f;
        for (int k = 0; k < 768; k += 4) {
            a0 = fmaf(e[k+0], w1[(k+0) * 24 + t], a0);
            a1 = fmaf(e[k+1], w1[(k+1) * 24 + t], a1);
            a2 = fmaf(e[k+2], w1[(k+2) * 24 + t], a2);
            a3 = fmaf(e[k+3], w1[(k+3) * 24 + t], a3);
        }
        hid[t] = gelu_exact(((a0 + a1) + (a2 + a3)) + b1[t]);
    }
    __syncthreads();
    const float alpha = alp[0];
    for (int c = t; c < 384; c += 64) {
        float z = b2[c];
#pragma unroll
        for (int j = 0; j < 24; ++j) z = fmaf(hid[j], w2[j * 384 + c], z);
        gw[b * 384 + c] = fmaf(alpha, sigmoidf(z), 1.0f);   // x_f = gw * x (clip/eps dropped)
    }
}

// ---------------- K3: LayerNorm stats mu[b,l], r[b,l] over C (xf = gw*x) ----------------
__global__ void __launch_bounds__(256) k3_stats(const float* __restrict__ x,
                                                const float* __restrict__ gw,
                                                float* __restrict__ mu,
                                                float* __restrict__ rr) {
    const int b = blockIdx.x >> 5, lt = blockIdx.x & 31;
    const int t = threadIdx.x, w8 = t >> 5, l5 = t & 31;
    const int l = lt * 32 + l5;
    const float* xb = x + (size_t)b * 393216 + l;
    const float* wb = gw + b * 384;
    float s = 0.0f, qa = 0.0f;
#pragma unroll 6
    for (int c = w8 * 48; c < w8 * 48 + 48; ++c) {
        float xf = wb[c] * xb[(size_t)c * 1024];
        s += xf;
        qa = fmaf(xf, xf, qa);
    }
    __shared__ float ls[8][32], lq[8][32];
    ls[w8][l5] = s; lq[w8][l5] = qa;
    __syncthreads();
    if (t < 32) {
        float S = 0.f, Q = 0.f;
#pragma unroll
        for (int i = 0; i < 8; ++i) { S += ls[i][t]; Q += lq[i][t]; }
        float m = S * (1.0f / 384.0f);
        float var = Q * (1.0f / 384.0f) - m * m;
        mu[b * 1024 + lt * 32 + t] = m;
        rr[b * 1024 + lt * 32 + t] = rsqrtf(var + 1e-5f);
    }
}

// ---------------- K4: S[b,c] = gw * sum_l x*r (float4 loads) ----------------
__global__ void __launch_bounds__(64) k4_S(const float* __restrict__ x,
                                           const float* __restrict__ gw,
                                           const float* __restrict__ rr,
                                           float* __restrict__ Sarr) {
    const int bc = blockIdx.x, lane = threadIdx.x;
    const int b = bc / 384;
    const float4* xr4 = (const float4*)(x + (size_t)bc * 1024);
    const float4* rb4 = (const float4*)(rr + b * 1024);
    float acc = 0.0f;
#pragma unroll
    for (int k = 0; k < 4; ++k) {
        float4 xv = xr4[lane + 64 * k];
        float4 rv = rb4[lane + 64 * k];
        acc = fmaf(xv.x, rv.x, acc);
        acc = fmaf(xv.y, rv.y, acc);
        acc = fmaf(xv.z, rv.z, acc);
        acc = fmaf(xv.w, rv.w, acc);
    }
#pragma unroll
    for (int off = 32; off > 0; off >>= 1) acc += __shfl_down(acc, off, 64);
    if (lane == 0) Sarr[bc] = gw[bc] * acc;
}

// ---------------- K5: ga[b,c] = 4*sigmoid(gelu(xg@wg+bg)@wc+bc) * gw, per b ----------------
__global__ void __launch_bounds__(384) k5_attn(const float* __restrict__ Sarr,
                                               const float* __restrict__ mu,
                                               const float* __restrict__ rr,
                                               const float* __restrict__ g,
                                               const float* __restrict__ beta,
                                               const float* __restrict__ wg,
                                               const float* __restrict__ bg,
                                               const float* __restrict__ wc,
                                               const float* __restrict__ bc_,
                                               const float* __restrict__ gw,
                                               float* __restrict__ ga) {
    __shared__ float red[6];
    __shared__ float xg[384];
    __shared__ float hid[48];
    const int b = blockIdx.x, t = threadIdx.x;
    const int wv = t >> 6, lane = t & 63;
    float p = 0.0f;
    for (int l = t; l < 1024; l += 384) p += mu[b * 1024 + l] * rr[b * 1024 + l];
#pragma unroll
    for (int off = 32; off > 0; off >>= 1) p += __shfl_down(p, off, 64);
    if (lane == 0) red[wv] = p;
    __syncthreads();
    float T = red[0] + red[1] + red[2] + red[3] + red[4] + red[5];
    xg[t] = fmaf(g[t], (Sarr[b * 384 + t] - T) * (1.0f / 1024.0f), 0.0f) + beta[t];
    __syncthreads();
    if (t < 48) {
        float a0 = 0.f, a1 = 0.f, a2 = 0.f, a3 = 0.f;
        for (int k = 0; k < 384; k += 4) {
            a0 = fmaf(xg[k+0], wg[(k+0) * 48 + t], a0);
            a1 = fmaf(xg[k+1], wg[(k+1) * 48 + t], a1);
            a2 = fmaf(xg[k+2], wg[(k+2) * 48 + t], a2);
            a3 = fmaf(xg[k+3], wg[(k+3) * 48 + t], a3);
        }
        hid[t] = gelu_exact(((a0 + a1) + (a2 + a3)) + bg[t]);
    }
    __syncthreads();
    float z = bc_[t];
#pragma unroll
    for (int j = 0; j < 48; ++j) z = fmaf(hid[j], wc[j * 384 + t], z);
    ga[b * 384 + t] = 4.0f * sigmoidf(z) * gw[b * 384 + t];
}

// ---------------- K6: out[b,l,c] = x[b,c,l] * ga[b,c] (LDS transpose, float4 stores) ----------
__global__ void __launch_bounds__(256) k6_out(const float* __restrict__ x,
                                              const float* __restrict__ ga,
                                              float* __restrict__ out) {
    __shared__ float tile[64][65];
    const int id = blockIdx.x;
    const int b = id / 96, rem = id - 96 * b;
    const int lt = rem / 6, ct = rem - 6 * lt;
    const int t = threadIdx.x, w = t >> 6, lane = t & 63;
    const float* xb = x + ((size_t)b * 384 + ct * 64) * 1024 + lt * 64;
#pragma unroll
    for (int i = 0; i < 16; ++i) {
        int cc = w + 4 * i;
        float coeff = ga[b * 384 + ct * 64 + cc];
        tile[cc][lane] = coeff * xb[(size_t)cc * 1024 + lane];
    }
    __syncthreads();
    const int c4 = (t & 15) * 4;
    const int lb = t >> 4;
    float* ob = out + ((size_t)b * 1024 + lt * 64) * 384 + ct * 64;
#pragma unroll
    for (int rep = 0; rep < 4; ++rep) {
        int ll = rep * 16 + lb;
        float4 v;
        v.x = tile[c4 + 0][ll];
        v.y = tile[c4 + 1][ll];
        v.z = tile[c4 + 2][ll];
        v.w = tile[c4 + 3][ll];
        *(float4*)(ob + (size_t)ll * 384 + c4) = v;
    }
}

extern "C" void kernel_launch(void* const* d_in, const int* in_sizes, int n_in,
                              void* d_out, int out_size, void* d_ws, size_t ws_size,
                              hipStream_t stream) {
    const float* x   = (const float*)d_in[0];
    const float* w1  = (const float*)d_in[1];
    const float* b1  = (const float*)d_in[2];
    const float* w2  = (const float*)d_in[3];
    const float* b2  = (const float*)d_in[4];
    const float* alp = (const float*)d_in[5];
    const float* lng = (const float*)d_in[6];
    const float* lnb = (const float*)d_in[7];
    const float* wg  = (const float*)d_in[8];
    const float* bg  = (const float*)d_in[9];
    const float* wc  = (const float*)d_in[10];
    const float* bc  = (const float*)d_in[11];
    float* out = (float*)d_out;

    float* ws     = (float*)d_ws;
    float* energy = ws;             // 32*768   = 24576
    float* gw     = ws + 24576;     // 32*384   = 12288
    float* mu     = ws + 36864;     // 32*1024  = 32768
    float* rr     = ws + 69632;     // 32*1024  = 32768
    float* Sarr   = ws + 102400;    // 32*384   = 12288
    float* ga     = ws + 114688;    // 32*384   = 12288

    k1_energy<<<6144, 64, 0, stream>>>(x, energy);
    k2_mlp<<<32, 64, 0, stream>>>(energy, w1, b1, w2, b2, alp, gw);
    k3_stats<<<1024, 256, 0, stream>>>(x, gw, mu, rr);
    k4_S<<<12288, 64, 0, stream>>>(x, gw, rr, Sarr);
    k5_attn<<<32, 384, 0, stream>>>(Sarr, mu, rr, lng, lnb, wg, bg, wc, bc, gw, ga);
    k6_out<<<3072, 256, 0, stream>>>(x, ga, out);
}

// Round 5
// 97.514 us; speedup vs baseline: 1.4608x; 1.0719x over previous
//
#include <hip/hip_runtime.h>
#include <hip/hip_bf16.h>
#include <math.h>

#define EPSF 1e-8f
// dims: B=32, C=384, H=W=32, L=1024, RF=24, RA=48

__device__ __forceinline__ float gelu_exact(float z) {
    return 0.5f * z * (1.0f + erff(z * 0.70710678118654752440f));
}
__device__ __forceinline__ float sigmoidf(float z) {
    return 1.0f / (1.0f + expf(-z));
}

// bf16 pack/unpack (no cvt_pk builtin on gfx950 -> inline asm)
__device__ __forceinline__ unsigned pk_bf16(float lo, float hi) {
    unsigned r;
    asm("v_cvt_pk_bf16_f32 %0, %1, %2" : "=v"(r) : "v"(lo), "v"(hi));
    return r;
}
__device__ __forceinline__ float ubf_lo(unsigned u) { return __uint_as_float(u << 16); }
__device__ __forceinline__ float ubf_hi(unsigned u) { return __uint_as_float(u & 0xFFFF0000u); }

// ---------- compile-time twiddles: cos/sin(2*pi*k/32) ----------
constexpr float cqv(int i) {
    return i == 0 ? 1.0f : i == 1 ? 0.980785280403230449f : i == 2 ? 0.923879532511286756f
         : i == 3 ? 0.831469612302545237f : i == 4 ? 0.707106781186547524f
         : i == 5 ? 0.555570233019602225f : i == 6 ? 0.382683432365089772f
         : i == 7 ? 0.195090322016128268f : 0.0f;  // i==8 -> 0
}
constexpr float c32f(int k) {
    k = ((k % 32) + 32) % 32;
    int kk = (k > 16) ? 32 - k : k;
    return (kk <= 8) ? cqv(kk) : -cqv(16 - kk);
}
constexpr float s32f(int k) { return c32f(k - 8); }

// ---------- stage 1: row DFT (along w), 1 row per lane ----------
template<int V, int W>
struct S1T {
    static __device__ __forceinline__ void run(const float (&r)[32], float& re, float& im) {
        constexpr float c = c32f(V * W);
        constexpr float s = s32f(V * W);
        if constexpr (c != 0.0f) re = fmaf(r[W], c, re);
        if constexpr (s != 0.0f) im = fmaf(r[W], -s, im);
        if constexpr (W + 1 < 32) S1T<V, W + 1>::run(r, re, im);
    }
};
template<int V>
struct S1V {
    static __device__ __forceinline__ void run(const float (&r)[32], unsigned* Rp, int base) {
        float re = 0.f, im = 0.f;
        S1T<V, 0>::run(r, re, im);
        Rp[base + V * 33] = pk_bf16(re, im);
        if constexpr (V + 1 < 17) S1V<V + 1>::run(r, Rp, base);
    }
};

// ---------- stage 2 kernel: complex dot with literal twiddles, N samples ----------
template<int U, int H, int HEND, int N>
struct S2T {
    static __device__ __forceinline__ void run(const float (&ar)[N], const float (&ai)[N],
                                               float& re, float& im) {
        constexpr float c = c32f(U * H);
        constexpr float s = s32f(U * H);
        if constexpr (c != 0.0f) { re = fmaf(ar[H], c, re); im = fmaf(ai[H], c, im); }
        if constexpr (s != 0.0f) { re = fmaf(ai[H], s, re); im = fmaf(ar[H], -s, im); }
        if constexpr (H + 1 < HEND) S2T<U, H + 1, HEND, N>::run(ar, ai, re, im);
    }
};

// high bins u in [8,32): 16-h half-partial, sign-fix odd u, pair combine, mag
template<int U>
struct HighU {
    static __device__ __forceinline__ void run(const float (&dr)[16], const float (&di)[16],
                                               float sgn, float& acc) {
        float re = 0.f, im = 0.f;
        S2T<U, 0, 16, 16>::run(dr, di, re, im);
        if constexpr (U & 1) { re *= sgn; im *= sgn; }
        float tr = re + __shfl_xor(re, 1);
        float ti = im + __shfl_xor(im, 1);
        acc += sqrtf(fmaf(tr, tr, ti * ti));
        if constexpr (U + 1 < 32) HighU<U + 1>::run(dr, di, sgn, acc);
    }
};

// low bins u in [0,8): 4-sample partial, rotate by w_k(u)=e^{-i pi u k/4}, 8-lane reduce, mag
template<int U>
struct LowU {
    static __device__ __forceinline__ void run(const float (&er)[4], const float (&ei)[4],
                                               float wre, float wim, float brc, float brs,
                                               float& acc) {
        float pr = 0.f, pi = 0.f;
        S2T<U, 0, 4, 4>::run(er, ei, pr, pi);
        float vr = pr * wre - pi * wim;
        float vi = pr * wim + pi * wre;
        vr += __shfl_xor(vr, 1); vi += __shfl_xor(vi, 1);
        vr += __shfl_xor(vr, 2); vi += __shfl_xor(vi, 2);
        vr += __shfl_xor(vr, 4); vi += __shfl_xor(vi, 4);
        acc += sqrtf(fmaf(vr, vr, vi * vi));
        if constexpr (U + 1 < 8) {
            float nre = fmaf(wre, brc, -wim * brs);
            float nim = fmaf(wre, brs, wim * brc);
            LowU<U + 1>::run(er, ei, nre, nim, brc, brs, acc);
        }
    }
};

// ---------------- K1: per-image rfft2 magnitudes -> energy[b, 2C] ----------------
// One wave = 2 images (grid 6144 -> 24 waves/CU). LDS: bf16-packed [img][v][h],
// v-stride 33 words (<=2-way banks), 4488 B/block.
// NOTE: no min-waves clause -- __launch_bounds__(64,6) capped VGPRs at ~85 and
// the allocator spilled ~176 B/thread to scratch (WRITE_SIZE 69 MB, R4).
__global__ void __launch_bounds__(64) k1_energy(const float* __restrict__ x,
                                                float* __restrict__ energy) {
    __shared__ __align__(16) unsigned Rp[2 * 561];
    const int t = threadIdx.x;
    const int img = t >> 5, h = t & 31;
    const int bc0 = blockIdx.x * 2;
    const float4* src = (const float4*)(x + (size_t)(bc0 + img) * 1024 + h * 32);
    float r[32];
#pragma unroll
    for (int k = 0; k < 8; ++k) {
        float4 a = src[k];
        r[4*k+0] = a.x + EPSF; r[4*k+1] = a.y + EPSF;
        r[4*k+2] = a.z + EPSF; r[4*k+3] = a.w + EPSF;
    }
    S1V<0>::run(r, Rp, img * 561 + h);
    __syncthreads();

    const int q = t & 31;
    // ---- high phase: 13 columns (v=4..16) x 2 h-halves = 26 tasks/img ----
    float acch = 0.f;
    {
        const int vq = (q < 26) ? (4 + (q >> 1)) : 4;
        const int h0 = (q < 26) ? ((q & 1) << 4) : 0;
        const unsigned* bp = &Rp[img * 561 + vq * 33 + h0];
        float dr[16], di[16];
#pragma unroll
        for (int k = 0; k < 16; ++k) { unsigned u = bp[k]; dr[k] = ubf_lo(u); di[k] = ubf_hi(u); }
        const float sgn = (h0 != 0) ? -1.0f : 1.0f;
        HighU<8>::run(dr, di, sgn, acch);
    }
    // ---- low phase: 4 columns (v=0..3) x 8 h-eighths = 32 tasks/img (all lanes) ----
    float accl = 0.f;
    {
        const int v2 = q >> 3, k8 = q & 7;
        const unsigned* lp = &Rp[img * 561 + v2 * 33 + k8 * 4];
        float er[4], ei[4];
#pragma unroll
        for (int j = 0; j < 4; ++j) { unsigned u = lp[j]; er[j] = ubf_lo(u); ei[j] = ubf_hi(u); }
        float sb, cb;
        sincosf(0.78539816339744831f * (float)k8, &sb, &cb);
        LowU<0>::run(er, ei, 1.0f, 0.0f, cb, -sb, accl);
    }
    // ---- reduce per img (32 lanes): high pairs double-counted (x2), low 8x ----
    float hv = (q < 26) ? acch : 0.f;
#pragma unroll
    for (int off = 1; off <= 16; off <<= 1) {
        hv   += __shfl_xor(hv, off);
        accl += __shfl_xor(accl, off);
    }
    if (q == 0) {
        const int bc = bc0 + img;
        const int b = bc / 384, c = bc - 384 * b;
        energy[b * 768 + c]       = accl * (1.0f / 8192.0f)  + EPSF;  // /(8 dup * 32 bins * 32 norm)
        energy[b * 768 + 384 + c] = hv   * (1.0f / 19968.0f) + EPSF;  // /(2 dup * 312 bins * 32 norm)
    }
}

// ---------------- K2: gw = 1 + alpha*sigmoid(gelu(energy@w1+b1)@w2+b2), per b ----------------
__global__ void __launch_bounds__(64) k2_mlp(const float* __restrict__ energy,
                                             const float* __restrict__ w1,
                                             const float* __restrict__ b1,
                                             const float* __restrict__ w2,
                                             const float* __restrict__ b2,
                                             const float* __restrict__ alp,
                                             float* __restrict__ gw) {
    __shared__ float e[768];
    __shared__ float hid[24];
    const int b = blockIdx.x, t = threadIdx.x;
    for (int i = t; i < 768; i += 64) e[i] = energy[b * 768 + i];
    __syncthreads();
    if (t < 24) {
        float a0 = 0.f, a1 = 0.f, a2 = 0.f, a3 = 0.f;
        for (int k = 0; k < 768; k += 4) {
            a0 = fmaf(e[k+0], w1[(k+0) * 24 + t], a0);
            a1 = fmaf(e[k+1], w1[(k+1) * 24 + t], a1);
            a2 = fmaf(e[k+2], w1[(k+2) * 24 + t], a2);
            a3 = fmaf(e[k+3], w1[(k+3) * 24 + t], a3);
        }
        hid[t] = gelu_exact(((a0 + a1) + (a2 + a3)) + b1[t]);
    }
    __syncthreads();
    const float alpha = alp[0];
    for (int c = t; c < 384; c += 64) {
        float z = b2[c];
#pragma unroll
        for (int j = 0; j < 24; ++j) z = fmaf(hid[j], w2[j * 384 + c], z);
        gw[b * 384 + c] = fmaf(alpha, sigmoidf(z), 1.0f);   // x_f = gw * x (clip/eps dropped)
    }
}

// ---------------- K3: LayerNorm stats mu[b,l], r[b,l] over C (xf = gw*x) ----------------
__global__ void __launch_bounds__(256) k3_stats(const float* __restrict__ x,
                                                const float* __restrict__ gw,
                                                float* __restrict__ mu,
                                                float* __restrict__ rr) {
    const int b = blockIdx.x >> 5, lt = blockIdx.x & 31;
    const int t = threadIdx.x, w8 = t >> 5, l5 = t & 31;
    const int l = lt * 32 + l5;
    const float* xb = x + (size_t)b * 393216 + l;
    const float* wb = gw + b * 384;
    float s = 0.0f, qa = 0.0f;
#pragma unroll 6
    for (int c = w8 * 48; c < w8 * 48 + 48; ++c) {
        float xf = wb[c] * xb[(size_t)c * 1024];
        s += xf;
        qa = fmaf(xf, xf, qa);
    }
    __shared__ float ls[8][32], lq[8][32];
    ls[w8][l5] = s; lq[w8][l5] = qa;
    __syncthreads();
    if (t < 32) {
        float S = 0.f, Q = 0.f;
#pragma unroll
        for (int i = 0; i < 8; ++i) { S += ls[i][t]; Q += lq[i][t]; }
        float m = S * (1.0f / 384.0f);
        float var = Q * (1.0f / 384.0f) - m * m;
        mu[b * 1024 + lt * 32 + t] = m;
        rr[b * 1024 + lt * 32 + t] = rsqrtf(var + 1e-5f);
    }
}

// ---------------- K4: S[b,c] = gw * sum_l x*r (float4 loads) ----------------
__global__ void __launch_bounds__(64) k4_S(const float* __restrict__ x,
                                           const float* __restrict__ gw,
                                           const float* __restrict__ rr,
                                           float* __restrict__ Sarr) {
    const int bc = blockIdx.x, lane = threadIdx.x;
    const int b = bc / 384;
    const float4* xr4 = (const float4*)(x + (size_t)bc * 1024);
    const float4* rb4 = (const float4*)(rr + b * 1024);
    float acc = 0.0f;
#pragma unroll
    for (int k = 0; k < 4; ++k) {
        float4 xv = xr4[lane + 64 * k];
        float4 rv = rb4[lane + 64 * k];
        acc = fmaf(xv.x, rv.x, acc);
        acc = fmaf(xv.y, rv.y, acc);
        acc = fmaf(xv.z, rv.z, acc);
        acc = fmaf(xv.w, rv.w, acc);
    }
#pragma unroll
    for (int off = 32; off > 0; off >>= 1) acc += __shfl_down(acc, off, 64);
    if (lane == 0) Sarr[bc] = gw[bc] * acc;
}

// ---------------- K5: ga[b,c] = 4*sigmoid(gelu(xg@wg+bg)@wc+bc) * gw, per b ----------------
__global__ void __launch_bounds__(384) k5_attn(const float* __restrict__ Sarr,
                                               const float* __restrict__ mu,
                                               const float* __restrict__ rr,
                                               const float* __restrict__ g,
                                               const float* __restrict__ beta,
                                               const float* __restrict__ wg,
                                               const float* __restrict__ bg,
                                               const float* __restrict__ wc,
                                               const float* __restrict__ bc_,
                                               const float* __restrict__ gw,
                                               float* __restrict__ ga) {
    __shared__ float red[6];
    __shared__ float xg[384];
    __shared__ float hid[48];
    const int b = blockIdx.x, t = threadIdx.x;
    const int wv = t >> 6, lane = t & 63;
    float p = 0.0f;
    for (int l = t; l < 1024; l += 384) p += mu[b * 1024 + l] * rr[b * 1024 + l];
#pragma unroll
    for (int off = 32; off > 0; off >>= 1) p += __shfl_down(p, off, 64);
    if (lane == 0) red[wv] = p;
    __syncthreads();
    float T = red[0] + red[1] + red[2] + red[3] + red[4] + red[5];
    xg[t] = fmaf(g[t], (Sarr[b * 384 + t] - T) * (1.0f / 1024.0f), 0.0f) + beta[t];
    __syncthreads();
    if (t < 48) {
        float a0 = 0.f, a1 = 0.f, a2 = 0.f, a3 = 0.f;
        for (int k = 0; k < 384; k += 4) {
            a0 = fmaf(xg[k+0], wg[(k+0) * 48 + t], a0);
            a1 = fmaf(xg[k+1], wg[(k+1) * 48 + t], a1);
            a2 = fmaf(xg[k+2], wg[(k+2) * 48 + t], a2);
            a3 = fmaf(xg[k+3], wg[(k+3) * 48 + t], a3);
        }
        hid[t] = gelu_exact(((a0 + a1) + (a2 + a3)) + bg[t]);
    }
    __syncthreads();
    float z = bc_[t];
#pragma unroll
    for (int j = 0; j < 48; ++j) z = fmaf(hid[j], wc[j * 384 + t], z);
    ga[b * 384 + t] = 4.0f * sigmoidf(z) * gw[b * 384 + t];
}

// ---------------- K6: out[b,l,c] = x[b,c,l] * ga[b,c] (LDS transpose, float4 stores) ----------
__global__ void __launch_bounds__(256) k6_out(const float* __restrict__ x,
                                              const float* __restrict__ ga,
                                              float* __restrict__ out) {
    __shared__ float tile[64][65];
    const int id = blockIdx.x;
    const int b = id / 96, rem = id - 96 * b;
    const int lt = rem / 6, ct = rem - 6 * lt;
    const int t = threadIdx.x, w = t >> 6, lane = t & 63;
    const float* xb = x + ((size_t)b * 384 + ct * 64) * 1024 + lt * 64;
#pragma unroll
    for (int i = 0; i < 16; ++i) {
        int cc = w + 4 * i;
        float coeff = ga[b * 384 + ct * 64 + cc];
        tile[cc][lane] = coeff * xb[(size_t)cc * 1024 + lane];
    }
    __syncthreads();
    const int c4 = (t & 15) * 4;
    const int lb = t >> 4;
    float* ob = out + ((size_t)b * 1024 + lt * 64) * 384 + ct * 64;
#pragma unroll
    for (int rep = 0; rep < 4; ++rep) {
        int ll = rep * 16 + lb;
        float4 v;
        v.x = tile[c4 + 0][ll];
        v.y = tile[c4 + 1][ll];
        v.z = tile[c4 + 2][ll];
        v.w = tile[c4 + 3][ll];
        *(float4*)(ob + (size_t)ll * 384 + c4) = v;
    }
}

extern "C" void kernel_launch(void* const* d_in, const int* in_sizes, int n_in,
                              void* d_out, int out_size, void* d_ws, size_t ws_size,
                              hipStream_t stream) {
    const float* x   = (const float*)d_in[0];
    const float* w1  = (const float*)d_in[1];
    const float* b1  = (const float*)d_in[2];
    const float* w2  = (const float*)d_in[3];
    const float* b2  = (const float*)d_in[4];
    const float* alp = (const float*)d_in[5];
    const float* lng = (const float*)d_in[6];
    const float* lnb = (const float*)d_in[7];
    const float* wg  = (const float*)d_in[8];
    const float* bg  = (const float*)d_in[9];
    const float* wc  = (const float*)d_in[10];
    const float* bc  = (const float*)d_in[11];
    float* out = (float*)d_out;

    float* ws     = (float*)d_ws;
    float* energy = ws;             // 32*768   = 24576
    float* gw     = ws + 24576;     // 32*384   = 12288
    float* mu     = ws + 36864;     // 32*1024  = 32768
    float* rr     = ws + 69632;     // 32*1024  = 32768
    float* Sarr   = ws + 102400;    // 32*384   = 12288
    float* ga     = ws + 114688;    // 32*384   = 12288

    k1_energy<<<6144, 64, 0, stream>>>(x, energy);
    k2_mlp<<<32, 64, 0, stream>>>(energy, w1, b1, w2, b2, alp, gw);
    k3_stats<<<1024, 256, 0, stream>>>(x, gw, mu, rr);
    k4_S<<<12288, 64, 0, stream>>>(x, gw, rr, Sarr);
    k5_attn<<<32, 384, 0, stream>>>(Sarr, mu, rr, lng, lnb, wg, bg, wc, bc, gw, ga);
    k6_out<<<3072, 256, 0, stream>>>(x, ga, out);
}

// Round 6
// 97.074 us; speedup vs baseline: 1.4674x; 1.0045x over previous
//
#include <hip/hip_runtime.h>
#include <hip/hip_bf16.h>
#include <math.h>

#define EPSF 1e-8f
// dims: B=32, C=384, H=W=32, L=1024, RF=24, RA=48

__device__ __forceinline__ float gelu_exact(float z) {
    return 0.5f * z * (1.0f + erff(z * 0.70710678118654752440f));
}
__device__ __forceinline__ float sigmoidf(float z) {
    return 1.0f / (1.0f + expf(-z));
}

// bf16 pack/unpack (no cvt_pk builtin on gfx950 -> inline asm)
__device__ __forceinline__ unsigned pk_bf16(float lo, float hi) {
    unsigned r;
    asm("v_cvt_pk_bf16_f32 %0, %1, %2" : "=v"(r) : "v"(lo), "v"(hi));
    return r;
}
__device__ __forceinline__ float ubf_lo(unsigned u) { return __uint_as_float(u << 16); }
__device__ __forceinline__ float ubf_hi(unsigned u) { return __uint_as_float(u & 0xFFFF0000u); }

// ---------- compile-time twiddles: cos/sin(2*pi*k/32) ----------
constexpr float cqv(int i) {
    return i == 0 ? 1.0f : i == 1 ? 0.980785280403230449f : i == 2 ? 0.923879532511286756f
         : i == 3 ? 0.831469612302545237f : i == 4 ? 0.707106781186547524f
         : i == 5 ? 0.555570233019602225f : i == 6 ? 0.382683432365089772f
         : i == 7 ? 0.195090322016128268f : 0.0f;  // i==8 -> 0
}
constexpr float c32f(int k) {
    k = ((k % 32) + 32) % 32;
    int kk = (k > 16) ? 32 - k : k;
    return (kk <= 8) ? cqv(kk) : -cqv(16 - kk);
}
constexpr float s32f(int k) { return c32f(k - 8); }

// ---------- stage 1: row DFT (along w), 1 row per lane ----------
template<int V, int W>
struct S1T {
    static __device__ __forceinline__ void run(const float (&r)[32], float& re, float& im) {
        constexpr float c = c32f(V * W);
        constexpr float s = s32f(V * W);
        if constexpr (c != 0.0f) re = fmaf(r[W], c, re);
        if constexpr (s != 0.0f) im = fmaf(r[W], -s, im);
        if constexpr (W + 1 < 32) S1T<V, W + 1>::run(r, re, im);
    }
};
template<int V>
struct S1V {
    static __device__ __forceinline__ void run(const float (&r)[32], unsigned* Rp, int base) {
        float re = 0.f, im = 0.f;
        S1T<V, 0>::run(r, re, im);
        Rp[base + V * 33] = pk_bf16(re, im);
        if constexpr (V + 1 < 17) S1V<V + 1>::run(r, Rp, base);
    }
};

// ---------- stage 2 kernel: complex dot with literal twiddles, N samples ----------
template<int U, int H, int HEND, int N>
struct S2T {
    static __device__ __forceinline__ void run(const float (&ar)[N], const float (&ai)[N],
                                               float& re, float& im) {
        constexpr float c = c32f(U * H);
        constexpr float s = s32f(U * H);
        if constexpr (c != 0.0f) { re = fmaf(ar[H], c, re); im = fmaf(ai[H], c, im); }
        if constexpr (s != 0.0f) { re = fmaf(ai[H], s, re); im = fmaf(ar[H], -s, im); }
        if constexpr (H + 1 < HEND) S2T<U, H + 1, HEND, N>::run(ar, ai, re, im);
    }
};

// high bins u in [8,32): 16-h half-partial, sign-fix odd u, pair combine, mag
template<int U>
struct HighU {
    static __device__ __forceinline__ void run(const float (&dr)[16], const float (&di)[16],
                                               float sgn, float& acc) {
        float re = 0.f, im = 0.f;
        S2T<U, 0, 16, 16>::run(dr, di, re, im);
        if constexpr (U & 1) { re *= sgn; im *= sgn; }
        float tr = re + __shfl_xor(re, 1);
        float ti = im + __shfl_xor(im, 1);
        acc += sqrtf(fmaf(tr, tr, ti * ti));
        if constexpr (U + 1 < 32) HighU<U + 1>::run(dr, di, sgn, acc);
    }
};

// low bins u in [0,8): 4-sample partial, rotate by w_k(u)=e^{-i pi u k/4}, 8-lane reduce, mag
template<int U>
struct LowU {
    static __device__ __forceinline__ void run(const float (&er)[4], const float (&ei)[4],
                                               float wre, float wim, float brc, float brs,
                                               float& acc) {
        float pr = 0.f, pi = 0.f;
        S2T<U, 0, 4, 4>::run(er, ei, pr, pi);
        float vr = pr * wre - pi * wim;
        float vi = pr * wim + pi * wre;
        vr += __shfl_xor(vr, 1); vi += __shfl_xor(vi, 1);
        vr += __shfl_xor(vr, 2); vi += __shfl_xor(vi, 2);
        vr += __shfl_xor(vr, 4); vi += __shfl_xor(vi, 4);
        acc += sqrtf(fmaf(vr, vr, vi * vi));
        if constexpr (U + 1 < 8) {
            float nre = fmaf(wre, brc, -wim * brs);
            float nim = fmaf(wre, brs, wim * brc);
            LowU<U + 1>::run(er, ei, nre, nim, brc, brs, acc);
        }
    }
};

// ---------------- K1: per-image rfft2 magnitudes -> energy[b, 2C] ----------------
// One wave = 2 images (grid 6144 -> 24 waves/CU). LDS: bf16-packed [img][v][h],
// v-stride 33 words (<=2-way banks), 4488 B/block.
// NOTE: no min-waves clause -- __launch_bounds__(64,6) capped VGPRs at ~85 and
// the allocator spilled ~176 B/thread to scratch (WRITE_SIZE 69 MB, R4).
__global__ void __launch_bounds__(64) k1_energy(const float* __restrict__ x,
                                                float* __restrict__ energy) {
    __shared__ __align__(16) unsigned Rp[2 * 561];
    const int t = threadIdx.x;
    const int img = t >> 5, h = t & 31;
    const int bc0 = blockIdx.x * 2;
    const float4* src = (const float4*)(x + (size_t)(bc0 + img) * 1024 + h * 32);
    float r[32];
#pragma unroll
    for (int k = 0; k < 8; ++k) {
        float4 a = src[k];
        r[4*k+0] = a.x + EPSF; r[4*k+1] = a.y + EPSF;
        r[4*k+2] = a.z + EPSF; r[4*k+3] = a.w + EPSF;
    }
    S1V<0>::run(r, Rp, img * 561 + h);
    __syncthreads();

    const int q = t & 31;
    // ---- high phase: 13 columns (v=4..16) x 2 h-halves = 26 tasks/img ----
    float acch = 0.f;
    {
        const int vq = (q < 26) ? (4 + (q >> 1)) : 4;
        const int h0 = (q < 26) ? ((q & 1) << 4) : 0;
        const unsigned* bp = &Rp[img * 561 + vq * 33 + h0];
        float dr[16], di[16];
#pragma unroll
        for (int k = 0; k < 16; ++k) { unsigned u = bp[k]; dr[k] = ubf_lo(u); di[k] = ubf_hi(u); }
        const float sgn = (h0 != 0) ? -1.0f : 1.0f;
        HighU<8>::run(dr, di, sgn, acch);
    }
    // ---- low phase: 4 columns (v=0..3) x 8 h-eighths = 32 tasks/img (all lanes) ----
    float accl = 0.f;
    {
        const int v2 = q >> 3, k8 = q & 7;
        const unsigned* lp = &Rp[img * 561 + v2 * 33 + k8 * 4];
        float er[4], ei[4];
#pragma unroll
        for (int j = 0; j < 4; ++j) { unsigned u = lp[j]; er[j] = ubf_lo(u); ei[j] = ubf_hi(u); }
        float sb, cb;
        sincosf(0.78539816339744831f * (float)k8, &sb, &cb);
        LowU<0>::run(er, ei, 1.0f, 0.0f, cb, -sb, accl);
    }
    // ---- reduce per img (32 lanes): high pairs double-counted (x2), low 8x ----
    float hv = (q < 26) ? acch : 0.f;
#pragma unroll
    for (int off = 1; off <= 16; off <<= 1) {
        hv   += __shfl_xor(hv, off);
        accl += __shfl_xor(accl, off);
    }
    if (q == 0) {
        const int bc = bc0 + img;
        const int b = bc / 384, c = bc - 384 * b;
        energy[b * 768 + c]       = accl * (1.0f / 8192.0f)  + EPSF;  // /(8 dup * 32 bins * 32 norm)
        energy[b * 768 + 384 + c] = hv   * (1.0f / 19968.0f) + EPSF;  // /(2 dup * 312 bins * 32 norm)
    }
}

// ---------------- K2: gw = 1 + alpha*sigmoid(gelu(energy@w1+b1)@w2+b2), per b ----------------
__global__ void __launch_bounds__(64) k2_mlp(const float* __restrict__ energy,
                                             const float* __restrict__ w1,
                                             const float* __restrict__ b1,
                                             const float* __restrict__ w2,
                                             const float* __restrict__ b2,
                                             const float* __restrict__ alp,
                                             float* __restrict__ gw) {
    __shared__ float e[768];
    __shared__ float hid[24];
    const int b = blockIdx.x, t = threadIdx.x;
    for (int i = t; i < 768; i += 64) e[i] = energy[b * 768 + i];
    __syncthreads();
    if (t < 24) {
        float a0 = 0.f, a1 = 0.f, a2 = 0.f, a3 = 0.f;
        for (int k = 0; k < 768; k += 4) {
            a0 = fmaf(e[k+0], w1[(k+0) * 24 + t], a0);
            a1 = fmaf(e[k+1], w1[(k+1) * 24 + t], a1);
            a2 = fmaf(e[k+2], w1[(k+2) * 24 + t], a2);
            a3 = fmaf(e[k+3], w1[(k+3) * 24 + t], a3);
        }
        hid[t] = gelu_exact(((a0 + a1) + (a2 + a3)) + b1[t]);
    }
    __syncthreads();
    const float alpha = alp[0];
    for (int c = t; c < 384; c += 64) {
        float z = b2[c];
#pragma unroll
        for (int j = 0; j < 24; ++j) z = fmaf(hid[j], w2[j * 384 + c], z);
        gw[b * 384 + c] = fmaf(alpha, sigmoidf(z), 1.0f);   // x_f = gw * x (clip/eps dropped)
    }
}

// ---------------- K34: fused LN stats + partial S ----------------
// Block = (b, l-slice of 32), 384 threads.
// Phase A: mu/rr over C for the 32 l's (reads x[b,:,slice], 49 KB).
// Phase B: re-read same slice (L2-hot), Spart[b,sl,c] = sum_{l in sl} x*r.
__global__ void __launch_bounds__(384) k34_stats_S(const float* __restrict__ x,
                                                   const float* __restrict__ gw,
                                                   float* __restrict__ mu,
                                                   float* __restrict__ rr,
                                                   float* __restrict__ Spart) {
    const int b = blockIdx.x >> 5, sl = blockIdx.x & 31;
    const int t = threadIdx.x, g = t >> 5, l5 = t & 31;
    const float* xb = x + (size_t)b * 393216 + sl * 32;
    const float* wb = gw + b * 384;
    __shared__ float ls[12][32], lq[12][32];
    __shared__ float r_sh[32];
    // Phase A: thread (g,l5) sums c in [g*32, g*32+32) at l = sl*32+l5
    {
        float s = 0.0f, qa = 0.0f;
        const float* xp = xb + (size_t)g * 32 * 1024 + l5;
#pragma unroll 8
        for (int cc = 0; cc < 32; ++cc) {
            float xf = wb[g * 32 + cc] * xp[(size_t)cc * 1024];
            s += xf;
            qa = fmaf(xf, xf, qa);
        }
        ls[g][l5] = s; lq[g][l5] = qa;
    }
    __syncthreads();
    if (t < 32) {
        float S = 0.f, Q = 0.f;
#pragma unroll
        for (int i = 0; i < 12; ++i) { S += ls[i][t]; Q += lq[i][t]; }
        float m = S * (1.0f / 384.0f);
        float var = Q * (1.0f / 384.0f) - m * m;
        float rv = rsqrtf(var + 1e-5f);
        mu[b * 1024 + sl * 32 + t] = m;
        rr[b * 1024 + sl * 32 + t] = rv;
        r_sh[t] = rv;
    }
    __syncthreads();
    // Phase B: thread t = c reads its 32-l row chunk (128 B, L2-hot) and dots with r_sh
    {
        const float4* xc = (const float4*)(xb + (size_t)t * 1024);
        float acc = 0.f;
#pragma unroll
        for (int k = 0; k < 8; ++k) {
            float4 v = xc[k];
            acc = fmaf(v.x, r_sh[4*k+0], acc);
            acc = fmaf(v.y, r_sh[4*k+1], acc);
            acc = fmaf(v.z, r_sh[4*k+2], acc);
            acc = fmaf(v.w, r_sh[4*k+3], acc);
        }
        Spart[((size_t)b * 32 + sl) * 384 + t] = acc;   // raw (gw applied in k5)
    }
}

// ---------------- K5: ga[b,c] = 4*sigmoid(gelu(xg@wg+bg)@wc+bc) * gw, per b ----------------
__global__ void __launch_bounds__(384) k5_attn(const float* __restrict__ Spart,
                                               const float* __restrict__ mu,
                                               const float* __restrict__ rr,
                                               const float* __restrict__ g,
                                               const float* __restrict__ beta,
                                               const float* __restrict__ wg,
                                               const float* __restrict__ bg,
                                               const float* __restrict__ wc,
                                               const float* __restrict__ bc_,
                                               const float* __restrict__ gw,
                                               float* __restrict__ ga) {
    __shared__ float red[6];
    __shared__ float xg[384];
    __shared__ float hid[48];
    const int b = blockIdx.x, t = threadIdx.x;
    const int wv = t >> 6, lane = t & 63;
    float p = 0.0f;
    for (int l = t; l < 1024; l += 384) p += mu[b * 1024 + l] * rr[b * 1024 + l];
#pragma unroll
    for (int off = 32; off > 0; off >>= 1) p += __shfl_down(p, off, 64);
    if (lane == 0) red[wv] = p;
    // S[b,c] = sum over 32 slices of Spart
    float Sraw = 0.f;
    {
        const float* sp = Spart + (size_t)b * 32 * 384 + t;
#pragma unroll 8
        for (int sl = 0; sl < 32; ++sl) Sraw += sp[sl * 384];
    }
    __syncthreads();
    float T = red[0] + red[1] + red[2] + red[3] + red[4] + red[5];
    float Sc = gw[b * 384 + t] * Sraw;
    xg[t] = fmaf(g[t], (Sc - T) * (1.0f / 1024.0f), 0.0f) + beta[t];
    __syncthreads();
    if (t < 48) {
        float a0 = 0.f, a1 = 0.f, a2 = 0.f, a3 = 0.f;
        for (int k = 0; k < 384; k += 4) {
            a0 = fmaf(xg[k+0], wg[(k+0) * 48 + t], a0);
            a1 = fmaf(xg[k+1], wg[(k+1) * 48 + t], a1);
            a2 = fmaf(xg[k+2], wg[(k+2) * 48 + t], a2);
            a3 = fmaf(xg[k+3], wg[(k+3) * 48 + t], a3);
        }
        hid[t] = gelu_exact(((a0 + a1) + (a2 + a3)) + bg[t]);
    }
    __syncthreads();
    float z = bc_[t];
#pragma unroll
    for (int j = 0; j < 48; ++j) z = fmaf(hid[j], wc[j * 384 + t], z);
    ga[b * 384 + t] = 4.0f * sigmoidf(z) * gw[b * 384 + t];
}

// ---------------- K6: out[b,l,c] = x[b,c,l] * ga[b,c] (LDS transpose, float4 stores) ----------
__global__ void __launch_bounds__(256) k6_out(const float* __restrict__ x,
                                              const float* __restrict__ ga,
                                              float* __restrict__ out) {
    __shared__ float tile[64][65];
    const int id = blockIdx.x;
    const int b = id / 96, rem = id - 96 * b;
    const int lt = rem / 6, ct = rem - 6 * lt;
    const int t = threadIdx.x, w = t >> 6, lane = t & 63;
    const float* xb = x + ((size_t)b * 384 + ct * 64) * 1024 + lt * 64;
#pragma unroll
    for (int i = 0; i < 16; ++i) {
        int cc = w + 4 * i;
        float coeff = ga[b * 384 + ct * 64 + cc];
        tile[cc][lane] = coeff * xb[(size_t)cc * 1024 + lane];
    }
    __syncthreads();
    const int c4 = (t & 15) * 4;
    const int lb = t >> 4;
    float* ob = out + ((size_t)b * 1024 + lt * 64) * 384 + ct * 64;
#pragma unroll
    for (int rep = 0; rep < 4; ++rep) {
        int ll = rep * 16 + lb;
        float4 v;
        v.x = tile[c4 + 0][ll];
        v.y = tile[c4 + 1][ll];
        v.z = tile[c4 + 2][ll];
        v.w = tile[c4 + 3][ll];
        *(float4*)(ob + (size_t)ll * 384 + c4) = v;
    }
}

extern "C" void kernel_launch(void* const* d_in, const int* in_sizes, int n_in,
                              void* d_out, int out_size, void* d_ws, size_t ws_size,
                              hipStream_t stream) {
    const float* x   = (const float*)d_in[0];
    const float* w1  = (const float*)d_in[1];
    const float* b1  = (const float*)d_in[2];
    const float* w2  = (const float*)d_in[3];
    const float* b2  = (const float*)d_in[4];
    const float* alp = (const float*)d_in[5];
    const float* lng = (const float*)d_in[6];
    const float* lnb = (const float*)d_in[7];
    const float* wg  = (const float*)d_in[8];
    const float* bg  = (const float*)d_in[9];
    const float* wc  = (const float*)d_in[10];
    const float* bc  = (const float*)d_in[11];
    float* out = (float*)d_out;

    float* ws     = (float*)d_ws;
    float* energy = ws;             // 32*768        = 24576
    float* gw     = ws + 24576;     // 32*384        = 12288
    float* mu     = ws + 36864;     // 32*1024       = 32768
    float* rr     = ws + 69632;     // 32*1024       = 32768
    float* Spart  = ws + 102400;    // 32*32*384     = 393216
    float* ga     = ws + 495616;    // 32*384        = 12288

    k1_energy<<<6144, 64, 0, stream>>>(x, energy);
    k2_mlp<<<32, 64, 0, stream>>>(energy, w1, b1, w2, b2, alp, gw);
    k34_stats_S<<<1024, 384, 0, stream>>>(x, gw, mu, rr, Spart);
    k5_attn<<<32, 384, 0, stream>>>(Spart, mu, rr, lng, lnb, wg, bg, wc, bc, gw, ga);
    k6_out<<<3072, 256, 0, stream>>>(x, ga, out);
}